// Round 5
// baseline (17432.028 us; speedup 1.0000x reference)
//
#include <hip/hip_runtime.h>
#include <math.h>

// 3-layer LSTM (B=64,H=512,T=512,F=513) + FC(512)->ReLU->FC(513).
// R4: ONE persistent kernel for all 512 timesteps (diagonal schedule inside),
//     split-bf16 MFMA (3-product, ~fp32 accurate), WEIGHTS REGISTER-RESIDENT.
//  Grid 192 = 3 layers x 64 j-blocks; block = 32 gate-cols (2 j-tiles) x 64 b
//  x full K; 4 waves K-split; per-wave B-fragments live in 144 VGPRs for the
//  whole kernel. c lives in LDS. h ping-pongs via global (device-fenced epoch
//  barrier between super-steps). x chunks transposed in-kernel every 64 steps.

#define BB 64
#define HH 512
#define TT 512
#define FF 513
#define KX 544                 // padded x-K (17 tiles of 32)
#define KT1 33                 // L1 k-tiles (17 x + 16 h)
#define KT23 32
#define SBH 32768              // shorts per h slot (64*512)
#define XCH2 (64 * 64 * KX)    // shorts per x ring slot: 2,228,224
#define OFF2 2162688
#define OFF3 4259840
#define TOTB 6356992
#define GRID 192

typedef __attribute__((ext_vector_type(8))) short s16x8;
typedef __attribute__((ext_vector_type(4))) short s16x4;
typedef __attribute__((ext_vector_type(4))) float f32x4;

#define MFB(a, b, c) __builtin_amdgcn_mfma_f32_16x16x32_bf16(a, b, c, 0, 0, 0)

__device__ __forceinline__ float sigf(float x) { return 1.0f / (1.0f + expf(-x)); }

__device__ __forceinline__ float bf2f(short s) {
    return __uint_as_float(((unsigned)(unsigned short)s) << 16);
}
__device__ __forceinline__ short f2bf(float w) {   // RNE
    unsigned u = __float_as_uint(w);
    return (short)((u + 0x7fff + ((u >> 16) & 1)) >> 16);
}
__device__ __forceinline__ void bfsplit(float w, short& hi, short& lo) {
    hi = f2bf(w);
    lo = f2bf(w - bf2f(hi));
}
__device__ __forceinline__ s16x8 cat44(s16x4 a, s16x4 b) {
    s16x8 r;
    r[0]=a[0]; r[1]=a[1]; r[2]=a[2]; r[3]=a[3];
    r[4]=b[0]; r[5]=b[1]; r[6]=b[2]; r[7]=b[3];
    return r;
}

// ---------- prep: initial h -> bf16 hi/lo [b][512], slot 0 ----------
__global__ __launch_bounds__(256) void prep_state_h(
    const float* __restrict__ h1, const float* __restrict__ h2,
    const float* __restrict__ h3, short* __restrict__ Hh, short* __restrict__ Hl)
{
    int idx = blockIdx.x * 256 + threadIdx.x;          // 3*32768
    int l = idx >> 15, e = idx & 32767;
    const float* s = l == 0 ? h1 : l == 1 ? h2 : h3;
    short hi, lo; bfsplit(s[e], hi, lo);
    Hh[(size_t)(l * 2) * SBH + e] = hi;
    Hl[(size_t)(l * 2) * SBH + e] = lo;
}

// ---------- prep: initial c transpose [b][u] -> cT[l][u][b] ----------
__global__ __launch_bounds__(256) void prep_state_c(
    const float* __restrict__ c1, const float* __restrict__ c2,
    const float* __restrict__ c3, float* __restrict__ cT)
{
    __shared__ float tile[64][65];
    int l = blockIdx.x >> 3, ut = blockIdx.x & 7;
    const float* s = l == 0 ? c1 : l == 1 ? c2 : c3;
    int u0 = ut * 64, tid = threadIdx.x;
#pragma unroll
    for (int p = 0; p < 16; ++p) {
        int b = p * 4 + (tid >> 6), u = tid & 63;
        tile[u][b] = s[(size_t)b * HH + u0 + u];
    }
    __syncthreads();
#pragma unroll
    for (int p = 0; p < 16; ++p) {
        int ul = p * 4 + (tid >> 6), b = tid & 63;
        cT[(size_t)l * (HH * BB) + (size_t)(u0 + ul) * BB + b] = tile[ul][b];
    }
}

// ---------- prep: bias sums, gate-interleaved j' = 4u+g ----------
__global__ __launch_bounds__(256) void prep_bias(
    const float* __restrict__ bi1, const float* __restrict__ bh1,
    const float* __restrict__ bi2, const float* __restrict__ bh2,
    const float* __restrict__ bi3, const float* __restrict__ bh3,
    float* __restrict__ bsum)
{
    int idx = blockIdx.x * 256 + threadIdx.x;          // 3*2048
    if (idx >= 6144) return;
    int l = idx >> 11, jq = idx & 2047;
    int u = jq >> 2, g = jq & 3;
    const float* bi = l == 0 ? bi1 : l == 1 ? bi2 : bi3;
    const float* bh = l == 0 ? bh1 : l == 1 ? bh2 : bh3;
    bsum[idx] = bi[g * HH + u] + bh[g * HH + u];
}

// ---------- prep: weight blobs (fragment-linear, split hi/lo) ----------
__global__ __launch_bounds__(256) void prep_blob(
    const float* __restrict__ Wih1, const float* __restrict__ Whh1,
    const float* __restrict__ Wih2, const float* __restrict__ Whh2,
    const float* __restrict__ Wih3, const float* __restrict__ Whh3,
    short* __restrict__ Bh, short* __restrict__ Bl)
{
    int idx = blockIdx.x * 256 + threadIdx.x;          // TOTB exact
    int l, e, KTl;
    if (idx < OFF2)      { l = 0; e = idx;        KTl = KT1;  }
    else if (idx < OFF3) { l = 1; e = idx - OFF2; KTl = KT23; }
    else                 { l = 2; e = idx - OFF3; KTl = KT23; }
    int jtkt = e >> 9, r = e & 511;
    int lane = r >> 3, i = r & 7;
    int jt = jtkt / KTl, kt = jtkt - jt * KTl;
    int n = lane & 15, g = (lane >> 4) & 3;
    int jq = jt * 16 + n;
    int u = jq >> 2, gate = jq & 3;
    int row = gate * HH + u;
    int kk = kt * 32 + ((i < 4) ? (g * 4 + i) : (16 + g * 4 + (i - 4)));
    float w;
    if (l == 0) {
        if (kk < KX) w = (kk < FF) ? Wih1[(size_t)row * FF + kk] : 0.f;
        else         w = Whh1[(size_t)row * HH + (kk - KX)];
    } else if (l == 1) {
        w = (kk < HH) ? Wih2[(size_t)row * HH + kk] : Whh2[(size_t)row * HH + kk - HH];
    } else {
        w = (kk < HH) ? Wih3[(size_t)row * HH + kk] : Whh3[(size_t)row * HH + kk - HH];
    }
    short hi, lo; bfsplit(w, hi, lo);
    Bh[idx] = hi; Bl[idx] = lo;
}

// ---------- prep: x chunk 0 -> slot 0: [tt][b][544] hi/lo ----------
__global__ __launch_bounds__(256) void prep_x(
    const float* __restrict__ x, short* __restrict__ Xh, short* __restrict__ Xl, int c)
{
    __shared__ float tile[64][65];
    int b = blockIdx.x / 9, fg = blockIdx.x - b * 9;
    int t0 = c * 64, tid = threadIdx.x;
#pragma unroll
    for (int p = 0; p < 16; ++p) {
        int idx = p * 256 + tid;
        int fl = idx >> 6, tt = idx & 63;
        int f = fg * 64 + fl;
        tile[fl][tt] = (f < FF) ? x[((size_t)b * FF + f) * TT + t0 + tt] : 0.f;
    }
    __syncthreads();
#pragma unroll
    for (int p = 0; p < 2; ++p) {
        int idx = p * 256 + tid;
        int fg8 = idx & 7, tt = idx >> 3;
        int k0 = fg * 64 + fg8 * 8;
        if (k0 < KX) {
            s16x8 vh, vl;
#pragma unroll
            for (int q = 0; q < 8; ++q) {
                short hi, lo; bfsplit(tile[fg8 * 8 + q][tt], hi, lo);
                vh[q] = hi; vl[q] = lo;
            }
            size_t off = ((size_t)tt * BB + b) * KX + k0;
            *(s16x8*)(Xh + off) = vh;
            *(s16x8*)(Xl + off) = vl;
        }
    }
}

// ---------- THE persistent kernel ----------
__global__ __launch_bounds__(256, 1) void lstm_persist(
    const float* __restrict__ x,
    const short* __restrict__ Bh, const short* __restrict__ Bl,
    short* __restrict__ Xh, short* __restrict__ Xl,
    short* __restrict__ Hh, short* __restrict__ Hl,
    const float* __restrict__ bsum, const float* __restrict__ cTin,
    unsigned* __restrict__ cnt)
{
    __shared__ float PfF[4 * 32 * 65];     // 33280 B; also aliased as x-tile [64][65]
    __shared__ float cLDS[8 * 64];
    __shared__ float biasLDS[32];
    __shared__ short hstH[64 * 8];
    __shared__ short hstL[64 * 8];

    const int bid = (int)blockIdx.x;
    const int layer = bid >> 6;            // 0..2
    const int jb = bid & 63;               // 0..63 -> j' cols [jb*32, jb*32+32)
    const int tid = (int)threadIdx.x;
    const int lane = tid & 63;
    const int wv = __builtin_amdgcn_readfirstlane(tid >> 6);
    const int rl = lane & 15, g = lane >> 4;
    const int u0 = jb * 8;

    // per-wave K split
    const int KTl = (layer == 0) ? KT1 : KT23;
    int kt0, ktn;
    if (layer == 0) { if (wv == 0) { kt0 = 0; ktn = 9; } else { kt0 = 9 + 8 * (wv - 1); ktn = 8; } }
    else            { kt0 = wv * 8; ktn = 8; }
    const size_t blobOff = (layer == 0) ? 0 : ((layer == 1) ? (size_t)OFF2 : (size_t)OFF3);

    // ---- weights -> registers (once) ----
    s16x8 WHr[2][9], WLr[2][9];
#pragma unroll
    for (int jj = 0; jj < 2; ++jj) {
        const int jtG = jb * 2 + jj;
#pragma unroll
        for (int it = 0; it < 9; ++it) {
            if (it < ktn) {
                size_t o = blobOff + ((size_t)(jtG * KTl + kt0 + it)) * 512 + lane * 8;
                WHr[jj][it] = *(const s16x8*)(Bh + o);
                WLr[jj][it] = *(const s16x8*)(Bl + o);
            }
        }
    }

    // ---- c slice + bias -> LDS (once) ----
    for (int e = tid; e < 512; e += 256)
        cLDS[e] = cTin[(size_t)layer * (HH * BB) + (size_t)u0 * 64 + e];
    if (tid < 32) biasLDS[tid] = bsum[layer * 2048 + jb * 32 + tid];
    __syncthreads();

    for (int s = 0; s < TT + 2; ++s) {
        const int t = s - layer;
        if (t >= 0 && t < TT) {
            // ---- A pointers (wave-uniform base) ----
            const short* srcAh; const short* srcAl; int lda2, kbase;
            if (layer == 0) {
                if (wv < 2) {
                    size_t xb = (size_t)((t >> 6) & 1) * XCH2 + (size_t)(t & 63) * (64 * KX);
                    srcAh = Xh + xb; srcAl = Xl + xb; lda2 = KX; kbase = kt0 * 32;
                } else {
                    size_t hb = (size_t)(0 * 2 + (t & 1)) * SBH;
                    srcAh = Hh + hb; srcAl = Hl + hb; lda2 = HH; kbase = kt0 * 32 - 544;
                }
            } else if (layer == 1) {
                if (wv < 2) { size_t hb = (size_t)(0 * 2 + ((t + 1) & 1)) * SBH;
                              srcAh = Hh + hb; srcAl = Hl + hb; kbase = kt0 * 32; }
                else        { size_t hb = (size_t)(1 * 2 + (t & 1)) * SBH;
                              srcAh = Hh + hb; srcAl = Hl + hb; kbase = kt0 * 32 - 512; }
                lda2 = HH;
            } else {
                if (wv < 2) { size_t hb = (size_t)(1 * 2 + ((t + 1) & 1)) * SBH;
                              srcAh = Hh + hb; srcAl = Hl + hb; kbase = kt0 * 32; }
                else        { size_t hb = (size_t)(2 * 2 + (t & 1)) * SBH;
                              srcAh = Hh + hb; srcAl = Hl + hb; kbase = kt0 * 32 - 512; }
                lda2 = HH;
            }
            const short* pAH = srcAh + (size_t)rl * lda2 + kbase + g * 4;
            const short* pAL = srcAl + (size_t)rl * lda2 + kbase + g * 4;
            const int R16 = 16 * lda2;

            f32x4 acc[2][4];
#pragma unroll
            for (int jj = 0; jj < 2; ++jj)
#pragma unroll
                for (int bt = 0; bt < 4; ++bt) acc[jj][bt] = (f32x4){0.f, 0.f, 0.f, 0.f};

#pragma unroll
            for (int it = 0; it < 9; ++it) {
                if (it < ktn) {
                    const int ko = it * 32;
                    s16x8 aH[4], aL[4];
#pragma unroll
                    for (int bt = 0; bt < 4; ++bt) {
                        const short* ph = pAH + ko + bt * R16;
                        const short* pl = pAL + ko + bt * R16;
                        aH[bt] = cat44(*(const s16x4*)ph, *(const s16x4*)(ph + 16));
                        aL[bt] = cat44(*(const s16x4*)pl, *(const s16x4*)(pl + 16));
                    }
#pragma unroll
                    for (int jj = 0; jj < 2; ++jj) {
#pragma unroll
                        for (int bt = 0; bt < 4; ++bt) {
                            acc[jj][bt] = MFB(aH[bt], WHr[jj][it], acc[jj][bt]);
                            acc[jj][bt] = MFB(aL[bt], WHr[jj][it], acc[jj][bt]);
                            acc[jj][bt] = MFB(aH[bt], WLr[jj][it], acc[jj][bt]);
                        }
                    }
                }
            }

            // ---- partial reduce across 4 waves ----
#pragma unroll
            for (int jj = 0; jj < 2; ++jj)
#pragma unroll
                for (int bt = 0; bt < 4; ++bt)
#pragma unroll
                    for (int r = 0; r < 4; ++r)
                        PfF[(wv * 32 + jj * 16 + rl) * 65 + bt * 16 + g * 4 + r] = acc[jj][bt][r];
            __syncthreads();

            {   // gates + pointwise: thread = (ul = tid>>5, bl = tid&31), 2 b-halves
                const int ul = tid >> 5, bl = tid & 31;
#pragma unroll
                for (int half = 0; half < 2; ++half) {
                    const int b = bl + half * 32;
                    float G[4];
#pragma unroll
                    for (int gi = 0; gi < 4; ++gi) {
                        const int jl = ul * 4 + gi;
                        float v = PfF[(0 * 32 + jl) * 65 + b] + PfF[(1 * 32 + jl) * 65 + b]
                                + PfF[(2 * 32 + jl) * 65 + b] + PfF[(3 * 32 + jl) * 65 + b];
                        G[gi] = v + biasLDS[jl];
                    }
                    float cold = cLDS[ul * 64 + b];
                    float cn = sigf(G[1]) * cold + sigf(G[0]) * tanhf(G[2]);
                    float hn = sigf(G[3]) * tanhf(cn);
                    cLDS[ul * 64 + b] = cn;
                    short hi, lo; bfsplit(hn, hi, lo);
                    hstH[b * 8 + ul] = hi;
                    hstL[b * 8 + ul] = lo;
                }
            }
            __syncthreads();
            if (tid < 64) {   // write h slice (8 u-cols x 64 b) to output slot
                const int b = tid;
                const size_t hb = (size_t)(layer * 2 + ((t + 1) & 1)) * SBH + (size_t)b * HH + u0;
                *(s16x8*)(Hh + hb) = *(const s16x8*)(hstH + b * 8);
                *(s16x8*)(Hl + hb) = *(const s16x8*)(hstL + b * 8);
            }
        }

        // ---- distributed x-transpose of next chunk (every 64 super-steps) ----
        if ((s & 63) == 0 && s <= 384) {
            const int c = (s >> 6) + 1;            // chunks 1..7
            const int slot = c & 1;
            __syncthreads();                        // Pf reads done; safe to alias
            float* tileF = PfF;                     // [64][65]
#pragma unroll 1
            for (int i = 0; i < 3; ++i) {
                const int task = bid * 3 + i;       // 0..575
                const int b = task / 9, fblk = task % 9;
                const int f0 = fblk * 64;
#pragma unroll
                for (int rr = 0; rr < 16; ++rr) {
                    const int fl = (tid >> 6) + rr * 4;
                    const int tt2 = tid & 63;
                    const int f = f0 + fl;
                    tileF[fl * 65 + tt2] = (f < FF) ? x[((size_t)b * FF + f) * TT + c * 64 + tt2] : 0.f;
                }
                __syncthreads();
                {
                    const int q = tid & 3, tt2 = tid >> 2;
                    const int fq = f0 + q * 16;
                    if (fq < KX) {
                        s16x8 vh0, vl0, vh1, vl1;
#pragma unroll
                        for (int m = 0; m < 8; ++m) {
                            short hi, lo; bfsplit(tileF[(q * 16 + m) * 65 + tt2], hi, lo);
                            vh0[m] = hi; vl0[m] = lo;
                        }
#pragma unroll
                        for (int m = 0; m < 8; ++m) {
                            short hi, lo; bfsplit(tileF[(q * 16 + 8 + m) * 65 + tt2], hi, lo);
                            vh1[m] = hi; vl1[m] = lo;
                        }
                        size_t o = (size_t)slot * XCH2 + ((size_t)tt2 * 64 + b) * KX + fq;
                        *(s16x8*)(Xh + o) = vh0;  *(s16x8*)(Xh + o + 8) = vh1;
                        *(s16x8*)(Xl + o) = vl0;  *(s16x8*)(Xl + o + 8) = vl1;
                    }
                }
                __syncthreads();
            }
        }

        // ---- device-scope epoch barrier ----
        if (s < TT + 1) {
            __syncthreads();
            if (tid == 0) {
                __threadfence();   // release h writes to device scope
                __hip_atomic_fetch_add(cnt, 1u, __ATOMIC_RELAXED, __HIP_MEMORY_SCOPE_AGENT);
                const unsigned tgt = (unsigned)GRID * (unsigned)(s + 1);
                while (__hip_atomic_load(cnt, __ATOMIC_RELAXED, __HIP_MEMORY_SCOPE_AGENT) < tgt)
                    __builtin_amdgcn_s_sleep(1);
                __threadfence();   // acquire: invalidate L1/L2 before next step's reads
            }
            __syncthreads();
        }
    }
}

// ---------- final FCs ----------
__global__ __launch_bounds__(256) void fc1_k(
    const short* __restrict__ H3h, const short* __restrict__ H3l,
    const float* __restrict__ W, const float* __restrict__ bias,
    float* __restrict__ hid)
{
    const int lane = (int)threadIdx.x & 63;                  // = b
    const int wv = __builtin_amdgcn_readfirstlane((int)threadIdx.x >> 6);
    const int n = (int)blockIdx.x * 4 + wv;                  // 0..511
    float acc = 0.f;
    const float* wr = W + (size_t)n * HH;
    for (int k = 0; k < HH; k += 8) {
        s16x8 vh = *(const s16x8*)(H3h + (size_t)lane * HH + k);
        s16x8 vl = *(const s16x8*)(H3l + (size_t)lane * HH + k);
#pragma unroll
        for (int i = 0; i < 8; ++i)
            acc = fmaf(bf2f(vh[i]) + bf2f(vl[i]), wr[k + i], acc);
    }
    acc += bias[n];
    hid[(size_t)lane * HH + n] = fmaxf(acc, 0.f);
}

__global__ __launch_bounds__(256) void fc2_k(
    const float* __restrict__ hid, const float* __restrict__ W,
    const float* __restrict__ bias, float* __restrict__ out)
{
    const int lane = (int)threadIdx.x & 63;                  // = b
    const int wv = __builtin_amdgcn_readfirstlane((int)threadIdx.x >> 6);
    const int n = (int)blockIdx.x * 4 + wv;                  // 0..515
    if (n >= FF) return;
    float acc = 0.f;
    const float* wr = W + (size_t)n * HH;
    const float* hp = hid + (size_t)lane * HH;
    for (int k = 0; k < HH; k += 8) {
        float4 a = *(const float4*)(hp + k);
        float4 b = *(const float4*)(hp + k + 4);
        acc = fmaf(a.x, wr[k+0], acc); acc = fmaf(a.y, wr[k+1], acc);
        acc = fmaf(a.z, wr[k+2], acc); acc = fmaf(a.w, wr[k+3], acc);
        acc = fmaf(b.x, wr[k+4], acc); acc = fmaf(b.y, wr[k+5], acc);
        acc = fmaf(b.z, wr[k+6], acc); acc = fmaf(b.w, wr[k+7], acc);
    }
    out[(size_t)lane * FF + n] = acc + bias[n];
}

extern "C" void kernel_launch(void* const* d_in, const int* in_sizes, int n_in,
                              void* d_out, int out_size, void* d_ws, size_t ws_size,
                              hipStream_t stream)
{
    const float* x     = (const float*)d_in[0];
    const float* Wih1  = (const float*)d_in[1];
    const float* Whh1  = (const float*)d_in[2];
    const float* bih1  = (const float*)d_in[3];
    const float* bhh1  = (const float*)d_in[4];
    const float* Wih2  = (const float*)d_in[5];
    const float* Whh2  = (const float*)d_in[6];
    const float* bih2  = (const float*)d_in[7];
    const float* bhh2  = (const float*)d_in[8];
    const float* Wih3  = (const float*)d_in[9];
    const float* Whh3  = (const float*)d_in[10];
    const float* bih3  = (const float*)d_in[11];
    const float* bhh3  = (const float*)d_in[12];
    const float* fc1_w = (const float*)d_in[13];
    const float* fc1_b = (const float*)d_in[14];
    const float* fc2_w = (const float*)d_in[15];
    const float* fc2_b = (const float*)d_in[16];

    char* p = (char*)d_ws;
    unsigned* cnt = (unsigned*)p;       p += 128;
    float* cT   = (float*)p;            p += (size_t)3 * HH * BB * 4;
    float* hid  = (float*)p;            p += (size_t)HH * BB * 4;
    float* bsum = (float*)p;            p += 6144 * 4;
    short* Hh   = (short*)p;            p += (size_t)6 * SBH * 2;
    short* Hl   = (short*)p;            p += (size_t)6 * SBH * 2;
    short* Xh   = (short*)p;            p += (size_t)2 * XCH2 * 2;
    short* Xl   = (short*)p;            p += (size_t)2 * XCH2 * 2;
    short* Bh   = (short*)p;            p += (size_t)TOTB * 2;
    short* Bl   = (short*)p;            p += (size_t)TOTB * 2;
    if ((size_t)(p - (char*)d_ws) > ws_size) return;

    hipMemsetAsync(cnt, 0, 128, stream);
    prep_state_h<<<384, 256, 0, stream>>>(
        (const float*)d_in[17], (const float*)d_in[19], (const float*)d_in[21], Hh, Hl);
    prep_state_c<<<24, 256, 0, stream>>>(
        (const float*)d_in[18], (const float*)d_in[20], (const float*)d_in[22], cT);
    prep_bias<<<24, 256, 0, stream>>>(bih1, bhh1, bih2, bhh2, bih3, bhh3, bsum);
    prep_blob<<<TOTB / 256, 256, 0, stream>>>(Wih1, Whh1, Wih2, Whh2, Wih3, Whh3, Bh, Bl);
    prep_x<<<576, 256, 0, stream>>>(x, Xh, Xl, 0);

    lstm_persist<<<GRID, 256, 0, stream>>>(x, Bh, Bl, Xh, Xl, Hh, Hl, bsum, cT, cnt);

    // final h3 @ t=511 -> slot (511+1)&1 = 0 -> layer2 slot0 = +4*SBH
    fc1_k<<<128, 256, 0, stream>>>(Hh + (size_t)4 * SBH, Hl + (size_t)4 * SBH,
                                   fc1_w, fc1_b, hid);
    fc2_k<<<129, 256, 0, stream>>>(hid, fc2_w, fc2_b, (float*)d_out);
}

// Round 7
// 13373.213 us; speedup vs baseline: 1.3035x; 1.3035x over previous
//
#include <hip/hip_runtime.h>
#include <math.h>

// 3-layer LSTM (B=64,H=512,T=512,F=513) + FC(512)->ReLU->FC(513).
// R6: R4 (persistent kernel, register-resident split-bf16 weights, MFMA)
//     + CONTENTION-FREE epoch barrier: per-block padded arrival slots
//     (parallel stores, no RMW), block0 wave-0 gathers 192 slots (3/lane),
//     publishes `go`; all others poll only `go`.
//     (R4's flat 192-way single-line atomicAdd chain was ~29us/step.)

#define BB 64
#define HH 512
#define TT 512
#define FF 513
#define KX 544                 // padded x-K (17 tiles of 32)
#define KT1 33                 // L1 k-tiles (17 x + 16 h)
#define KT23 32
#define SBH 32768              // shorts per h slot (64*512)
#define XCH2 (64 * 64 * KX)    // shorts per x ring slot: 2,228,224
#define OFF2 2162688
#define OFF3 4259840
#define TOTB 6356992
#define GRID 192

typedef __attribute__((ext_vector_type(8))) short s16x8;
typedef __attribute__((ext_vector_type(4))) short s16x4;
typedef __attribute__((ext_vector_type(4))) float f32x4;

#define MFB(a, b, c) __builtin_amdgcn_mfma_f32_16x16x32_bf16(a, b, c, 0, 0, 0)

__device__ __forceinline__ float sigf(float x) { return 1.0f / (1.0f + expf(-x)); }

__device__ __forceinline__ float bf2f(short s) {
    return __uint_as_float(((unsigned)(unsigned short)s) << 16);
}
__device__ __forceinline__ short f2bf(float w) {   // RNE
    unsigned u = __float_as_uint(w);
    return (short)((u + 0x7fff + ((u >> 16) & 1)) >> 16);
}
__device__ __forceinline__ void bfsplit(float w, short& hi, short& lo) {
    hi = f2bf(w);
    lo = f2bf(w - bf2f(hi));
}
__device__ __forceinline__ s16x8 cat44(s16x4 a, s16x4 b) {
    s16x8 r;
    r[0]=a[0]; r[1]=a[1]; r[2]=a[2]; r[3]=a[3];
    r[4]=b[0]; r[5]=b[1]; r[6]=b[2]; r[7]=b[3];
    return r;
}

// ---------- prep: initial h -> bf16 hi/lo [b][512], slot 0 ----------
__global__ __launch_bounds__(256) void prep_state_h(
    const float* __restrict__ h1, const float* __restrict__ h2,
    const float* __restrict__ h3, short* __restrict__ Hh, short* __restrict__ Hl)
{
    int idx = blockIdx.x * 256 + threadIdx.x;          // 3*32768
    int l = idx >> 15, e = idx & 32767;
    const float* s = l == 0 ? h1 : l == 1 ? h2 : h3;
    short hi, lo; bfsplit(s[e], hi, lo);
    Hh[(size_t)(l * 2) * SBH + e] = hi;
    Hl[(size_t)(l * 2) * SBH + e] = lo;
}

// ---------- prep: initial c transpose [b][u] -> cT[l][u][b] ----------
__global__ __launch_bounds__(256) void prep_state_c(
    const float* __restrict__ c1, const float* __restrict__ c2,
    const float* __restrict__ c3, float* __restrict__ cT)
{
    __shared__ float tile[64][65];
    int l = blockIdx.x >> 3, ut = blockIdx.x & 7;
    const float* s = l == 0 ? c1 : l == 1 ? c2 : c3;
    int u0 = ut * 64, tid = threadIdx.x;
#pragma unroll
    for (int p = 0; p < 16; ++p) {
        int b = p * 4 + (tid >> 6), u = tid & 63;
        tile[u][b] = s[(size_t)b * HH + u0 + u];
    }
    __syncthreads();
#pragma unroll
    for (int p = 0; p < 16; ++p) {
        int ul = p * 4 + (tid >> 6), b = tid & 63;
        cT[(size_t)l * (HH * BB) + (size_t)(u0 + ul) * BB + b] = tile[ul][b];
    }
}

// ---------- prep: bias sums, gate-interleaved j' = 4u+g ----------
__global__ __launch_bounds__(256) void prep_bias(
    const float* __restrict__ bi1, const float* __restrict__ bh1,
    const float* __restrict__ bi2, const float* __restrict__ bh2,
    const float* __restrict__ bi3, const float* __restrict__ bh3,
    float* __restrict__ bsum)
{
    int idx = blockIdx.x * 256 + threadIdx.x;          // 3*2048
    if (idx >= 6144) return;
    int l = idx >> 11, jq = idx & 2047;
    int u = jq >> 2, g = jq & 3;
    const float* bi = l == 0 ? bi1 : l == 1 ? bi2 : bi3;
    const float* bh = l == 0 ? bh1 : l == 1 ? bh2 : bh3;
    bsum[idx] = bi[g * HH + u] + bh[g * HH + u];
}

// ---------- prep: weight blobs (fragment-linear, split hi/lo) ----------
__global__ __launch_bounds__(256) void prep_blob(
    const float* __restrict__ Wih1, const float* __restrict__ Whh1,
    const float* __restrict__ Wih2, const float* __restrict__ Whh2,
    const float* __restrict__ Wih3, const float* __restrict__ Whh3,
    short* __restrict__ Bh, short* __restrict__ Bl)
{
    int idx = blockIdx.x * 256 + threadIdx.x;          // TOTB exact
    int l, e, KTl;
    if (idx < OFF2)      { l = 0; e = idx;        KTl = KT1;  }
    else if (idx < OFF3) { l = 1; e = idx - OFF2; KTl = KT23; }
    else                 { l = 2; e = idx - OFF3; KTl = KT23; }
    int jtkt = e >> 9, r = e & 511;
    int lane = r >> 3, i = r & 7;
    int jt = jtkt / KTl, kt = jtkt - jt * KTl;
    int n = lane & 15, g = (lane >> 4) & 3;
    int jq = jt * 16 + n;
    int u = jq >> 2, gate = jq & 3;
    int row = gate * HH + u;
    int kk = kt * 32 + ((i < 4) ? (g * 4 + i) : (16 + g * 4 + (i - 4)));
    float w;
    if (l == 0) {
        if (kk < KX) w = (kk < FF) ? Wih1[(size_t)row * FF + kk] : 0.f;
        else         w = Whh1[(size_t)row * HH + (kk - KX)];
    } else if (l == 1) {
        w = (kk < HH) ? Wih2[(size_t)row * HH + kk] : Whh2[(size_t)row * HH + kk - HH];
    } else {
        w = (kk < HH) ? Wih3[(size_t)row * HH + kk] : Whh3[(size_t)row * HH + kk - HH];
    }
    short hi, lo; bfsplit(w, hi, lo);
    Bh[idx] = hi; Bl[idx] = lo;
}

// ---------- prep: x chunk 0 -> slot 0: [tt][b][544] hi/lo ----------
__global__ __launch_bounds__(256) void prep_x(
    const float* __restrict__ x, short* __restrict__ Xh, short* __restrict__ Xl, int c)
{
    __shared__ float tile[64][65];
    int b = blockIdx.x / 9, fg = blockIdx.x - b * 9;
    int t0 = c * 64, tid = threadIdx.x;
#pragma unroll
    for (int p = 0; p < 16; ++p) {
        int idx = p * 256 + tid;
        int fl = idx >> 6, tt = idx & 63;
        int f = fg * 64 + fl;
        tile[fl][tt] = (f < FF) ? x[((size_t)b * FF + f) * TT + t0 + tt] : 0.f;
    }
    __syncthreads();
#pragma unroll
    for (int p = 0; p < 2; ++p) {
        int idx = p * 256 + tid;
        int fg8 = idx & 7, tt = idx >> 3;
        int k0 = fg * 64 + fg8 * 8;
        if (k0 < KX) {
            s16x8 vh, vl;
#pragma unroll
            for (int q = 0; q < 8; ++q) {
                short hi, lo; bfsplit(tile[fg8 * 8 + q][tt], hi, lo);
                vh[q] = hi; vl[q] = lo;
            }
            size_t off = ((size_t)tt * BB + b) * KX + k0;
            *(s16x8*)(Xh + off) = vh;
            *(s16x8*)(Xl + off) = vl;
        }
    }
}

// ---------- THE persistent kernel ----------
__global__ __launch_bounds__(256, 1) void lstm_persist(
    const float* __restrict__ x,
    const short* __restrict__ Bh, const short* __restrict__ Bl,
    short* __restrict__ Xh, short* __restrict__ Xl,
    short* __restrict__ Hh, short* __restrict__ Hl,
    const float* __restrict__ bsum, const float* __restrict__ cTin,
    unsigned* __restrict__ arrive,   // [GRID * 32] (128B-padded slots)
    unsigned* __restrict__ go)       // [32]
{
    __shared__ float PfF[4 * 32 * 65];     // 33280 B; also aliased as x-tile [64][65]
    __shared__ float cLDS[8 * 64];
    __shared__ float biasLDS[32];
    __shared__ short hstH[64 * 8];
    __shared__ short hstL[64 * 8];

    const int bid = (int)blockIdx.x;
    const int layer = bid >> 6;            // 0..2
    const int jb = bid & 63;               // 0..63 -> j' cols [jb*32, jb*32+32)
    const int tid = (int)threadIdx.x;
    const int lane = tid & 63;
    const int wv = __builtin_amdgcn_readfirstlane(tid >> 6);
    const int rl = lane & 15, g = lane >> 4;
    const int u0 = jb * 8;

    // per-wave K split
    const int KTl = (layer == 0) ? KT1 : KT23;
    int kt0, ktn;
    if (layer == 0) { if (wv == 0) { kt0 = 0; ktn = 9; } else { kt0 = 9 + 8 * (wv - 1); ktn = 8; } }
    else            { kt0 = wv * 8; ktn = 8; }
    const size_t blobOff = (layer == 0) ? 0 : ((layer == 1) ? (size_t)OFF2 : (size_t)OFF3);

    // ---- weights -> registers (once) ----
    s16x8 WHr[2][9], WLr[2][9];
#pragma unroll
    for (int jj = 0; jj < 2; ++jj) {
        const int jtG = jb * 2 + jj;
#pragma unroll
        for (int it = 0; it < 9; ++it) {
            if (it < ktn) {
                size_t o = blobOff + ((size_t)(jtG * KTl + kt0 + it)) * 512 + lane * 8;
                WHr[jj][it] = *(const s16x8*)(Bh + o);
                WLr[jj][it] = *(const s16x8*)(Bl + o);
            }
        }
    }

    // ---- c slice + bias -> LDS (once) ----
    for (int e = tid; e < 512; e += 256)
        cLDS[e] = cTin[(size_t)layer * (HH * BB) + (size_t)u0 * 64 + e];
    if (tid < 32) biasLDS[tid] = bsum[layer * 2048 + jb * 32 + tid];
    __syncthreads();

    for (int s = 0; s < TT + 2; ++s) {
        const int t = s - layer;
        if (t >= 0 && t < TT) {
            // ---- A pointers (wave-uniform base) ----
            const short* srcAh; const short* srcAl; int lda2, kbase;
            if (layer == 0) {
                if (wv < 2) {
                    size_t xb = (size_t)((t >> 6) & 1) * XCH2 + (size_t)(t & 63) * (64 * KX);
                    srcAh = Xh + xb; srcAl = Xl + xb; lda2 = KX; kbase = kt0 * 32;
                } else {
                    size_t hb = (size_t)(0 * 2 + (t & 1)) * SBH;
                    srcAh = Hh + hb; srcAl = Hl + hb; lda2 = HH; kbase = kt0 * 32 - 544;
                }
            } else if (layer == 1) {
                if (wv < 2) { size_t hb = (size_t)(0 * 2 + ((t + 1) & 1)) * SBH;
                              srcAh = Hh + hb; srcAl = Hl + hb; kbase = kt0 * 32; }
                else        { size_t hb = (size_t)(1 * 2 + (t & 1)) * SBH;
                              srcAh = Hh + hb; srcAl = Hl + hb; kbase = kt0 * 32 - 512; }
                lda2 = HH;
            } else {
                if (wv < 2) { size_t hb = (size_t)(1 * 2 + ((t + 1) & 1)) * SBH;
                              srcAh = Hh + hb; srcAl = Hl + hb; kbase = kt0 * 32; }
                else        { size_t hb = (size_t)(2 * 2 + (t & 1)) * SBH;
                              srcAh = Hh + hb; srcAl = Hl + hb; kbase = kt0 * 32 - 512; }
                lda2 = HH;
            }
            const short* pAH = srcAh + (size_t)rl * lda2 + kbase + g * 4;
            const short* pAL = srcAl + (size_t)rl * lda2 + kbase + g * 4;
            const int R16 = 16 * lda2;

            f32x4 acc[2][4];
#pragma unroll
            for (int jj = 0; jj < 2; ++jj)
#pragma unroll
                for (int bt = 0; bt < 4; ++bt) acc[jj][bt] = (f32x4){0.f, 0.f, 0.f, 0.f};

#pragma unroll
            for (int it = 0; it < 9; ++it) {
                if (it < ktn) {
                    const int ko = it * 32;
                    s16x8 aH[4], aL[4];
#pragma unroll
                    for (int bt = 0; bt < 4; ++bt) {
                        const short* ph = pAH + ko + bt * R16;
                        const short* pl = pAL + ko + bt * R16;
                        aH[bt] = cat44(*(const s16x4*)ph, *(const s16x4*)(ph + 16));
                        aL[bt] = cat44(*(const s16x4*)pl, *(const s16x4*)(pl + 16));
                    }
#pragma unroll
                    for (int jj = 0; jj < 2; ++jj) {
#pragma unroll
                        for (int bt = 0; bt < 4; ++bt) {
                            acc[jj][bt] = MFB(aH[bt], WHr[jj][it], acc[jj][bt]);
                            acc[jj][bt] = MFB(aL[bt], WHr[jj][it], acc[jj][bt]);
                            acc[jj][bt] = MFB(aH[bt], WLr[jj][it], acc[jj][bt]);
                        }
                    }
                }
            }

            // ---- partial reduce across 4 waves ----
#pragma unroll
            for (int jj = 0; jj < 2; ++jj)
#pragma unroll
                for (int bt = 0; bt < 4; ++bt)
#pragma unroll
                    for (int r = 0; r < 4; ++r)
                        PfF[(wv * 32 + jj * 16 + rl) * 65 + bt * 16 + g * 4 + r] = acc[jj][bt][r];
            __syncthreads();

            {   // gates + pointwise: thread = (ul = tid>>5, bl = tid&31), 2 b-halves
                const int ul = tid >> 5, bl = tid & 31;
#pragma unroll
                for (int half = 0; half < 2; ++half) {
                    const int b = bl + half * 32;
                    float G[4];
#pragma unroll
                    for (int gi = 0; gi < 4; ++gi) {
                        const int jl = ul * 4 + gi;
                        float v = PfF[(0 * 32 + jl) * 65 + b] + PfF[(1 * 32 + jl) * 65 + b]
                                + PfF[(2 * 32 + jl) * 65 + b] + PfF[(3 * 32 + jl) * 65 + b];
                        G[gi] = v + biasLDS[jl];
                    }
                    float cold = cLDS[ul * 64 + b];
                    float cn = sigf(G[1]) * cold + sigf(G[0]) * tanhf(G[2]);
                    float hn = sigf(G[3]) * tanhf(cn);
                    cLDS[ul * 64 + b] = cn;
                    short hi, lo; bfsplit(hn, hi, lo);
                    hstH[b * 8 + ul] = hi;
                    hstL[b * 8 + ul] = lo;
                }
            }
            __syncthreads();
            if (tid < 64) {   // write h slice (8 u-cols x 64 b) to output slot
                const int b = tid;
                const size_t hb = (size_t)(layer * 2 + ((t + 1) & 1)) * SBH + (size_t)b * HH + u0;
                *(s16x8*)(Hh + hb) = *(const s16x8*)(hstH + b * 8);
                *(s16x8*)(Hl + hb) = *(const s16x8*)(hstL + b * 8);
            }
        }

        // ---- distributed x-transpose of next chunk (every 64 super-steps) ----
        if ((s & 63) == 0 && s <= 384) {
            const int c = (s >> 6) + 1;            // chunks 1..7
            const int slot = c & 1;
            __syncthreads();                        // Pf reads done; safe to alias
            float* tileF = PfF;                     // [64][65]
#pragma unroll 1
            for (int i = 0; i < 3; ++i) {
                const int task = bid * 3 + i;       // 0..575
                const int b = task / 9, fblk = task % 9;
                const int f0 = fblk * 64;
#pragma unroll
                for (int rr = 0; rr < 16; ++rr) {
                    const int fl = (tid >> 6) + rr * 4;
                    const int tt2 = tid & 63;
                    const int f = f0 + fl;
                    tileF[fl * 65 + tt2] = (f < FF) ? x[((size_t)b * FF + f) * TT + c * 64 + tt2] : 0.f;
                }
                __syncthreads();
                {
                    const int q = tid & 3, tt2 = tid >> 2;
                    const int fq = f0 + q * 16;
                    if (fq < KX) {
                        s16x8 vh0, vl0, vh1, vl1;
#pragma unroll
                        for (int m = 0; m < 8; ++m) {
                            short hi, lo; bfsplit(tileF[(q * 16 + m) * 65 + tt2], hi, lo);
                            vh0[m] = hi; vl0[m] = lo;
                        }
#pragma unroll
                        for (int m = 0; m < 8; ++m) {
                            short hi, lo; bfsplit(tileF[(q * 16 + 8 + m) * 65 + tt2], hi, lo);
                            vh1[m] = hi; vl1[m] = lo;
                        }
                        size_t o = (size_t)slot * XCH2 + ((size_t)tt2 * 64 + b) * KX + fq;
                        *(s16x8*)(Xh + o) = vh0;  *(s16x8*)(Xh + o + 8) = vh1;
                        *(s16x8*)(Xl + o) = vl0;  *(s16x8*)(Xl + o + 8) = vl1;
                    }
                }
                __syncthreads();
            }
        }

        // ---- contention-free device-scope epoch barrier ----
        if (s < TT + 1) {
            __syncthreads();
            const unsigned want = (unsigned)(s + 1);
            if (tid == 0) {
                __threadfence();   // release h/x writes to device scope
                __hip_atomic_store(&arrive[bid * 32], want,
                                   __ATOMIC_RELAXED, __HIP_MEMORY_SCOPE_AGENT);
            }
            if (bid == 0 && tid < 64) {
                // wave-0 gather: each lane polls 3 slots
                for (;;) {
                    unsigned v0 = __hip_atomic_load(&arrive[(tid      ) * 32],
                                                    __ATOMIC_RELAXED, __HIP_MEMORY_SCOPE_AGENT);
                    unsigned v1 = __hip_atomic_load(&arrive[(tid +  64) * 32],
                                                    __ATOMIC_RELAXED, __HIP_MEMORY_SCOPE_AGENT);
                    unsigned v2 = __hip_atomic_load(&arrive[(tid + 128) * 32],
                                                    __ATOMIC_RELAXED, __HIP_MEMORY_SCOPE_AGENT);
                    bool ok = (v0 >= want) && (v1 >= want) && (v2 >= want);
                    if (__all(ok)) break;
                    __builtin_amdgcn_s_sleep(1);
                }
                if (tid == 0)
                    __hip_atomic_store(go, want,
                                       __ATOMIC_RELAXED, __HIP_MEMORY_SCOPE_AGENT);
            }
            if (tid == 0) {
                while (__hip_atomic_load(go, __ATOMIC_RELAXED,
                                         __HIP_MEMORY_SCOPE_AGENT) < want)
                    __builtin_amdgcn_s_sleep(2);
                __threadfence();   // acquire before next step's reads
            }
            __syncthreads();
        }
    }
}

// ---------- final FCs ----------
__global__ __launch_bounds__(256) void fc1_k(
    const short* __restrict__ H3h, const short* __restrict__ H3l,
    const float* __restrict__ W, const float* __restrict__ bias,
    float* __restrict__ hid)
{
    const int lane = (int)threadIdx.x & 63;                  // = b
    const int wv = __builtin_amdgcn_readfirstlane((int)threadIdx.x >> 6);
    const int n = (int)blockIdx.x * 4 + wv;                  // 0..511
    float acc = 0.f;
    const float* wr = W + (size_t)n * HH;
    for (int k = 0; k < HH; k += 8) {
        s16x8 vh = *(const s16x8*)(H3h + (size_t)lane * HH + k);
        s16x8 vl = *(const s16x8*)(H3l + (size_t)lane * HH + k);
#pragma unroll
        for (int i = 0; i < 8; ++i)
            acc = fmaf(bf2f(vh[i]) + bf2f(vl[i]), wr[k + i], acc);
    }
    acc += bias[n];
    hid[(size_t)lane * HH + n] = fmaxf(acc, 0.f);
}

__global__ __launch_bounds__(256) void fc2_k(
    const float* __restrict__ hid, const float* __restrict__ W,
    const float* __restrict__ bias, float* __restrict__ out)
{
    const int lane = (int)threadIdx.x & 63;                  // = b
    const int wv = __builtin_amdgcn_readfirstlane((int)threadIdx.x >> 6);
    const int n = (int)blockIdx.x * 4 + wv;                  // 0..515
    if (n >= FF) return;
    float acc = 0.f;
    const float* wr = W + (size_t)n * HH;
    const float* hp = hid + (size_t)lane * HH;
    for (int k = 0; k < HH; k += 8) {
        float4 a = *(const float4*)(hp + k);
        float4 b = *(const float4*)(hp + k + 4);
        acc = fmaf(a.x, wr[k+0], acc); acc = fmaf(a.y, wr[k+1], acc);
        acc = fmaf(a.z, wr[k+2], acc); acc = fmaf(a.w, wr[k+3], acc);
        acc = fmaf(b.x, wr[k+4], acc); acc = fmaf(b.y, wr[k+5], acc);
        acc = fmaf(b.z, wr[k+6], acc); acc = fmaf(b.w, wr[k+7], acc);
    }
    out[(size_t)lane * FF + n] = acc + bias[n];
}

extern "C" void kernel_launch(void* const* d_in, const int* in_sizes, int n_in,
                              void* d_out, int out_size, void* d_ws, size_t ws_size,
                              hipStream_t stream)
{
    const float* x     = (const float*)d_in[0];
    const float* Wih1  = (const float*)d_in[1];
    const float* Whh1  = (const float*)d_in[2];
    const float* bih1  = (const float*)d_in[3];
    const float* bhh1  = (const float*)d_in[4];
    const float* Wih2  = (const float*)d_in[5];
    const float* Whh2  = (const float*)d_in[6];
    const float* bih2  = (const float*)d_in[7];
    const float* bhh2  = (const float*)d_in[8];
    const float* Wih3  = (const float*)d_in[9];
    const float* Whh3  = (const float*)d_in[10];
    const float* bih3  = (const float*)d_in[11];
    const float* bhh3  = (const float*)d_in[12];
    const float* fc1_w = (const float*)d_in[13];
    const float* fc1_b = (const float*)d_in[14];
    const float* fc2_w = (const float*)d_in[15];
    const float* fc2_b = (const float*)d_in[16];

    char* p = (char*)d_ws;
    unsigned* arrive = (unsigned*)p;    p += (size_t)GRID * 32 * 4;   // 24576
    unsigned* go     = (unsigned*)p;    p += 128;
    p = (char*)d_ws + 32768;            // round barrier region
    float* cT   = (float*)p;            p += (size_t)3 * HH * BB * 4;
    float* hid  = (float*)p;            p += (size_t)HH * BB * 4;
    float* bsum = (float*)p;            p += 6144 * 4;
    short* Hh   = (short*)p;            p += (size_t)6 * SBH * 2;
    short* Hl   = (short*)p;            p += (size_t)6 * SBH * 2;
    short* Xh   = (short*)p;            p += (size_t)2 * XCH2 * 2;
    short* Xl   = (short*)p;            p += (size_t)2 * XCH2 * 2;
    short* Bh   = (short*)p;            p += (size_t)TOTB * 2;
    short* Bl   = (short*)p;            p += (size_t)TOTB * 2;
    if ((size_t)(p - (char*)d_ws) > ws_size) return;

    hipMemsetAsync(d_ws, 0, 32768, stream);
    prep_state_h<<<384, 256, 0, stream>>>(
        (const float*)d_in[17], (const float*)d_in[19], (const float*)d_in[21], Hh, Hl);
    prep_state_c<<<24, 256, 0, stream>>>(
        (const float*)d_in[18], (const float*)d_in[20], (const float*)d_in[22], cT);
    prep_bias<<<24, 256, 0, stream>>>(bih1, bhh1, bih2, bhh2, bih3, bhh3, bsum);
    prep_blob<<<TOTB / 256, 256, 0, stream>>>(Wih1, Whh1, Wih2, Whh2, Wih3, Whh3, Bh, Bl);
    prep_x<<<576, 256, 0, stream>>>(x, Xh, Xl, 0);

    lstm_persist<<<GRID, 256, 0, stream>>>(x, Bh, Bl, Xh, Xl, Hh, Hl, bsum, cT,
                                           arrive, go);

    // final h3 @ t=511 -> slot (511+1)&1 = 0 -> layer2 slot0 = +4*SBH
    fc1_k<<<128, 256, 0, stream>>>(Hh + (size_t)4 * SBH, Hl + (size_t)4 * SBH,
                                   fc1_w, fc1_b, hid);
    fc2_k<<<129, 256, 0, stream>>>(hid, fc2_w, fc2_b, (float*)d_out);
}

// Round 8
// 9389.989 us; speedup vs baseline: 1.8564x; 1.4242x over previous
//
#include <hip/hip_runtime.h>
#include <math.h>

// 3-layer LSTM (B=64,H=512,T=512,F=513) + FC(512)->ReLU->FC(513).
// R7: persistent kernel, register-resident split-bf16 MFMA weights (R4-R6),
//     with FENCE-FREE MALL-coherent h/x exchange:
//  - h and x-ring payloads via 8B agent-scope RELAXED atomics (write-through
//    to Infinity Cache, L2-bypassing reads) -> no __threadfence / wbl2 / inv,
//    no HBM round trip (R6 counters: 1.61GB @120GB/s == whole runtime).
//  - Selective per-layer flag waits (single-stage, monotone): block flags s+1
//    after s_waitcnt vmcnt(0); polls only groups it depends on.
//  - x-transpose done by layer-0 blocks only (task = own batch row).

#define BB 64
#define HH 512
#define TT 512
#define FF 513
#define KX 544                 // padded x-K (17 tiles of 32)
#define KT1 33                 // L1 k-tiles (17 x + 16 h)
#define KT23 32
#define SBH 32768              // shorts per h slot (64*512)
#define XCH2 (64 * 64 * KX)    // shorts per x ring slot: 2,228,224
#define OFF2 2162688
#define OFF3 4259840
#define TOTB 6356992
#define GRID 192

typedef __attribute__((ext_vector_type(8))) short s16x8;
typedef __attribute__((ext_vector_type(4))) short s16x4;
typedef __attribute__((ext_vector_type(4))) float f32x4;

#define MFB(a, b, c) __builtin_amdgcn_mfma_f32_16x16x32_bf16(a, b, c, 0, 0, 0)

__device__ __forceinline__ float sigf(float x) { return 1.0f / (1.0f + expf(-x)); }

__device__ __forceinline__ float bf2f(short s) {
    return __uint_as_float(((unsigned)(unsigned short)s) << 16);
}
__device__ __forceinline__ short f2bf(float w) {   // RNE
    unsigned u = __float_as_uint(w);
    return (short)((u + 0x7fff + ((u >> 16) & 1)) >> 16);
}
__device__ __forceinline__ void bfsplit(float w, short& hi, short& lo) {
    hi = f2bf(w);
    lo = f2bf(w - bf2f(hi));
}
__device__ __forceinline__ s16x8 cat44(s16x4 a, s16x4 b) {
    s16x8 r;
    r[0]=a[0]; r[1]=a[1]; r[2]=a[2]; r[3]=a[3];
    r[4]=b[0]; r[5]=b[1]; r[6]=b[2]; r[7]=b[3];
    return r;
}

// ---- MALL-coherent 8B payload ops (agent-scope relaxed atomics) ----
__device__ __forceinline__ s16x4 aload8(const short* p) {
    unsigned long long v = __hip_atomic_load((const unsigned long long*)p,
                            __ATOMIC_RELAXED, __HIP_MEMORY_SCOPE_AGENT);
    union { unsigned long long u; s16x4 s; } c; c.u = v; return c.s;
}
__device__ __forceinline__ void astore8(short* p, s16x4 v) {
    union { unsigned long long u; s16x4 s; } c; c.s = v;
    __hip_atomic_store((unsigned long long*)p, c.u,
                       __ATOMIC_RELAXED, __HIP_MEMORY_SCOPE_AGENT);
}
__device__ __forceinline__ s16x4 lo4(s16x8 v) {
    s16x4 r; r[0]=v[0]; r[1]=v[1]; r[2]=v[2]; r[3]=v[3]; return r;
}
__device__ __forceinline__ s16x4 hi4(s16x8 v) {
    s16x4 r; r[0]=v[4]; r[1]=v[5]; r[2]=v[6]; r[3]=v[7]; return r;
}

// ---------- prep: initial h -> bf16 hi/lo [b][512], slot 0 ----------
__global__ __launch_bounds__(256) void prep_state_h(
    const float* __restrict__ h1, const float* __restrict__ h2,
    const float* __restrict__ h3, short* __restrict__ Hh, short* __restrict__ Hl)
{
    int idx = blockIdx.x * 256 + threadIdx.x;          // 3*32768
    int l = idx >> 15, e = idx & 32767;
    const float* s = l == 0 ? h1 : l == 1 ? h2 : h3;
    short hi, lo; bfsplit(s[e], hi, lo);
    Hh[(size_t)(l * 2) * SBH + e] = hi;
    Hl[(size_t)(l * 2) * SBH + e] = lo;
}

// ---------- prep: initial c transpose [b][u] -> cT[l][u][b] ----------
__global__ __launch_bounds__(256) void prep_state_c(
    const float* __restrict__ c1, const float* __restrict__ c2,
    const float* __restrict__ c3, float* __restrict__ cT)
{
    __shared__ float tile[64][65];
    int l = blockIdx.x >> 3, ut = blockIdx.x & 7;
    const float* s = l == 0 ? c1 : l == 1 ? c2 : c3;
    int u0 = ut * 64, tid = threadIdx.x;
#pragma unroll
    for (int p = 0; p < 16; ++p) {
        int b = p * 4 + (tid >> 6), u = tid & 63;
        tile[u][b] = s[(size_t)b * HH + u0 + u];
    }
    __syncthreads();
#pragma unroll
    for (int p = 0; p < 16; ++p) {
        int ul = p * 4 + (tid >> 6), b = tid & 63;
        cT[(size_t)l * (HH * BB) + (size_t)(u0 + ul) * BB + b] = tile[ul][b];
    }
}

// ---------- prep: bias sums, gate-interleaved j' = 4u+g ----------
__global__ __launch_bounds__(256) void prep_bias(
    const float* __restrict__ bi1, const float* __restrict__ bh1,
    const float* __restrict__ bi2, const float* __restrict__ bh2,
    const float* __restrict__ bi3, const float* __restrict__ bh3,
    float* __restrict__ bsum)
{
    int idx = blockIdx.x * 256 + threadIdx.x;          // 3*2048
    if (idx >= 6144) return;
    int l = idx >> 11, jq = idx & 2047;
    int u = jq >> 2, g = jq & 3;
    const float* bi = l == 0 ? bi1 : l == 1 ? bi2 : bi3;
    const float* bh = l == 0 ? bh1 : l == 1 ? bh2 : bh3;
    bsum[idx] = bi[g * HH + u] + bh[g * HH + u];
}

// ---------- prep: weight blobs (fragment-linear, split hi/lo) ----------
__global__ __launch_bounds__(256) void prep_blob(
    const float* __restrict__ Wih1, const float* __restrict__ Whh1,
    const float* __restrict__ Wih2, const float* __restrict__ Whh2,
    const float* __restrict__ Wih3, const float* __restrict__ Whh3,
    short* __restrict__ Bh, short* __restrict__ Bl)
{
    int idx = blockIdx.x * 256 + threadIdx.x;          // TOTB exact
    int l, e, KTl;
    if (idx < OFF2)      { l = 0; e = idx;        KTl = KT1;  }
    else if (idx < OFF3) { l = 1; e = idx - OFF2; KTl = KT23; }
    else                 { l = 2; e = idx - OFF3; KTl = KT23; }
    int jtkt = e >> 9, r = e & 511;
    int lane = r >> 3, i = r & 7;
    int jt = jtkt / KTl, kt = jtkt - jt * KTl;
    int n = lane & 15, g = (lane >> 4) & 3;
    int jq = jt * 16 + n;
    int u = jq >> 2, gate = jq & 3;
    int row = gate * HH + u;
    int kk = kt * 32 + ((i < 4) ? (g * 4 + i) : (16 + g * 4 + (i - 4)));
    float w;
    if (l == 0) {
        if (kk < KX) w = (kk < FF) ? Wih1[(size_t)row * FF + kk] : 0.f;
        else         w = Whh1[(size_t)row * HH + (kk - KX)];
    } else if (l == 1) {
        w = (kk < HH) ? Wih2[(size_t)row * HH + kk] : Whh2[(size_t)row * HH + kk - HH];
    } else {
        w = (kk < HH) ? Wih3[(size_t)row * HH + kk] : Whh3[(size_t)row * HH + kk - HH];
    }
    short hi, lo; bfsplit(w, hi, lo);
    Bh[idx] = hi; Bl[idx] = lo;
}

// ---------- prep: x chunk 0 -> slot 0: [tt][b][544] hi/lo ----------
__global__ __launch_bounds__(256) void prep_x(
    const float* __restrict__ x, short* __restrict__ Xh, short* __restrict__ Xl, int c)
{
    __shared__ float tile[64][65];
    int b = blockIdx.x / 9, fg = blockIdx.x - b * 9;
    int t0 = c * 64, tid = threadIdx.x;
#pragma unroll
    for (int p = 0; p < 16; ++p) {
        int idx = p * 256 + tid;
        int fl = idx >> 6, tt = idx & 63;
        int f = fg * 64 + fl;
        tile[fl][tt] = (f < FF) ? x[((size_t)b * FF + f) * TT + t0 + tt] : 0.f;
    }
    __syncthreads();
#pragma unroll
    for (int p = 0; p < 2; ++p) {
        int idx = p * 256 + tid;
        int fg8 = idx & 7, tt = idx >> 3;
        int k0 = fg * 64 + fg8 * 8;
        if (k0 < KX) {
            s16x8 vh, vl;
#pragma unroll
            for (int q = 0; q < 8; ++q) {
                short hi, lo; bfsplit(tile[fg8 * 8 + q][tt], hi, lo);
                vh[q] = hi; vl[q] = lo;
            }
            size_t off = ((size_t)tt * BB + b) * KX + k0;
            *(s16x8*)(Xh + off) = vh;
            *(s16x8*)(Xl + off) = vl;
        }
    }
}

// ---------- THE persistent kernel ----------
__global__ __launch_bounds__(256, 1) void lstm_persist(
    const float* __restrict__ x,
    const short* __restrict__ Bh, const short* __restrict__ Bl,
    short* __restrict__ Xh, short* __restrict__ Xl,
    short* __restrict__ Hh, short* __restrict__ Hl,
    const float* __restrict__ bsum, const float* __restrict__ cTin,
    unsigned* __restrict__ arrive)   // [GRID * 32] (128B-padded slots)
{
    __shared__ float PfF[4 * 32 * 65];     // 33280 B; also aliased as x-tile [64][65]
    __shared__ float cLDS[8 * 64];
    __shared__ float biasLDS[32];
    __shared__ short hstH[64 * 8];
    __shared__ short hstL[64 * 8];

    const int bid = (int)blockIdx.x;
    const int layer = bid >> 6;            // 0..2
    const int jb = bid & 63;               // 0..63 -> j' cols [jb*32, jb*32+32)
    const int tid = (int)threadIdx.x;
    const int lane = tid & 63;
    const int wv = __builtin_amdgcn_readfirstlane(tid >> 6);
    const int rl = lane & 15, g = lane >> 4;
    const int u0 = jb * 8;

    // per-wave K split
    const int KTl = (layer == 0) ? KT1 : KT23;
    int kt0, ktn;
    if (layer == 0) { if (wv == 0) { kt0 = 0; ktn = 9; } else { kt0 = 9 + 8 * (wv - 1); ktn = 8; } }
    else            { kt0 = wv * 8; ktn = 8; }
    const size_t blobOff = (layer == 0) ? 0 : ((layer == 1) ? (size_t)OFF2 : (size_t)OFF3);

    // ---- weights -> registers (once) ----
    s16x8 WHr[2][9], WLr[2][9];
#pragma unroll
    for (int jj = 0; jj < 2; ++jj) {
        const int jtG = jb * 2 + jj;
#pragma unroll
        for (int it = 0; it < 9; ++it) {
            if (it < ktn) {
                size_t o = blobOff + ((size_t)(jtG * KTl + kt0 + it)) * 512 + lane * 8;
                WHr[jj][it] = *(const s16x8*)(Bh + o);
                WLr[jj][it] = *(const s16x8*)(Bl + o);
            }
        }
    }

    // ---- c slice + bias -> LDS (once) ----
    for (int e = tid; e < 512; e += 256)
        cLDS[e] = cTin[(size_t)layer * (HH * BB) + (size_t)u0 * 64 + e];
    if (tid < 32) biasLDS[tid] = bsum[layer * 2048 + jb * 32 + tid];
    __syncthreads();

    const bool need0 = (layer <= 1);   // group 0 flags
    const bool need2 = (layer >= 1);   // group 2 flags

    for (int s = 0; s < TT + 2; ++s) {
        // ---- selective wait: dependency groups must have flagged >= s ----
        if (s > 0) {
            if (tid < 64) {
                const unsigned want = (unsigned)s;
                for (;;) {
                    bool ok = true;
                    if (need0)
                        ok &= __hip_atomic_load(&arrive[(0 * 64 + tid) * 32],
                              __ATOMIC_RELAXED, __HIP_MEMORY_SCOPE_AGENT) >= want;
                    ok &= __hip_atomic_load(&arrive[(1 * 64 + tid) * 32],
                          __ATOMIC_RELAXED, __HIP_MEMORY_SCOPE_AGENT) >= want;
                    if (need2)
                        ok &= __hip_atomic_load(&arrive[(2 * 64 + tid) * 32],
                              __ATOMIC_RELAXED, __HIP_MEMORY_SCOPE_AGENT) >= want;
                    if (__all(ok)) break;
                    __builtin_amdgcn_s_sleep(1);
                }
            }
            __syncthreads();
        }

        const int t = s - layer;
        if (t >= 0 && t < TT) {
            // ---- A pointers (wave-uniform base) ----
            const short* srcAh; const short* srcAl; int lda2, kbase;
            if (layer == 0) {
                if (wv < 2) {
                    size_t xb = (size_t)((t >> 6) & 1) * XCH2 + (size_t)(t & 63) * (64 * KX);
                    srcAh = Xh + xb; srcAl = Xl + xb; lda2 = KX; kbase = kt0 * 32;
                } else {
                    size_t hb = (size_t)(0 * 2 + (t & 1)) * SBH;
                    srcAh = Hh + hb; srcAl = Hl + hb; lda2 = HH; kbase = kt0 * 32 - 544;
                }
            } else if (layer == 1) {
                if (wv < 2) { size_t hb = (size_t)(0 * 2 + ((t + 1) & 1)) * SBH;
                              srcAh = Hh + hb; srcAl = Hl + hb; kbase = kt0 * 32; }
                else        { size_t hb = (size_t)(1 * 2 + (t & 1)) * SBH;
                              srcAh = Hh + hb; srcAl = Hl + hb; kbase = kt0 * 32 - 512; }
                lda2 = HH;
            } else {
                if (wv < 2) { size_t hb = (size_t)(1 * 2 + ((t + 1) & 1)) * SBH;
                              srcAh = Hh + hb; srcAl = Hl + hb; kbase = kt0 * 32; }
                else        { size_t hb = (size_t)(2 * 2 + (t & 1)) * SBH;
                              srcAh = Hh + hb; srcAl = Hl + hb; kbase = kt0 * 32 - 512; }
                lda2 = HH;
            }
            const short* pAH = srcAh + (size_t)rl * lda2 + kbase + g * 4;
            const short* pAL = srcAl + (size_t)rl * lda2 + kbase + g * 4;
            const int R16 = 16 * lda2;

            f32x4 acc[2][4];
#pragma unroll
            for (int jj = 0; jj < 2; ++jj)
#pragma unroll
                for (int bt = 0; bt < 4; ++bt) acc[jj][bt] = (f32x4){0.f, 0.f, 0.f, 0.f};

#pragma unroll
            for (int it = 0; it < 9; ++it) {
                if (it < ktn) {
                    const int ko = it * 32;
                    s16x8 aH[4], aL[4];
#pragma unroll
                    for (int bt = 0; bt < 4; ++bt) {
                        const short* ph = pAH + ko + bt * R16;
                        const short* pl = pAL + ko + bt * R16;
                        aH[bt] = cat44(aload8(ph), aload8(ph + 16));
                        aL[bt] = cat44(aload8(pl), aload8(pl + 16));
                    }
#pragma unroll
                    for (int jj = 0; jj < 2; ++jj) {
#pragma unroll
                        for (int bt = 0; bt < 4; ++bt) {
                            acc[jj][bt] = MFB(aH[bt], WHr[jj][it], acc[jj][bt]);
                            acc[jj][bt] = MFB(aL[bt], WHr[jj][it], acc[jj][bt]);
                            acc[jj][bt] = MFB(aH[bt], WLr[jj][it], acc[jj][bt]);
                        }
                    }
                }
            }

            // ---- partial reduce across 4 waves ----
#pragma unroll
            for (int jj = 0; jj < 2; ++jj)
#pragma unroll
                for (int bt = 0; bt < 4; ++bt)
#pragma unroll
                    for (int r = 0; r < 4; ++r)
                        PfF[(wv * 32 + jj * 16 + rl) * 65 + bt * 16 + g * 4 + r] = acc[jj][bt][r];
            __syncthreads();

            {   // gates + pointwise: thread = (ul = tid>>5, bl = tid&31), 2 b-halves
                const int ul = tid >> 5, bl = tid & 31;
#pragma unroll
                for (int half = 0; half < 2; ++half) {
                    const int b = bl + half * 32;
                    float G[4];
#pragma unroll
                    for (int gi = 0; gi < 4; ++gi) {
                        const int jl = ul * 4 + gi;
                        float v = PfF[(0 * 32 + jl) * 65 + b] + PfF[(1 * 32 + jl) * 65 + b]
                                + PfF[(2 * 32 + jl) * 65 + b] + PfF[(3 * 32 + jl) * 65 + b];
                        G[gi] = v + biasLDS[jl];
                    }
                    float cold = cLDS[ul * 64 + b];
                    float cn = sigf(G[1]) * cold + sigf(G[0]) * tanhf(G[2]);
                    float hn = sigf(G[3]) * tanhf(cn);
                    cLDS[ul * 64 + b] = cn;
                    short hi, lo; bfsplit(hn, hi, lo);
                    hstH[b * 8 + ul] = hi;
                    hstL[b * 8 + ul] = lo;
                }
            }
            __syncthreads();
            if (tid < 64) {   // write h slice (8 u-cols x 64 b) -> MALL-coherent
                const int b = tid;
                const size_t hb = (size_t)(layer * 2 + ((t + 1) & 1)) * SBH + (size_t)b * HH + u0;
                s16x8 vh = *(const s16x8*)(hstH + b * 8);
                s16x8 vl = *(const s16x8*)(hstL + b * 8);
                astore8(Hh + hb,     lo4(vh));
                astore8(Hh + hb + 4, hi4(vh));
                astore8(Hl + hb,     lo4(vl));
                astore8(Hl + hb + 4, hi4(vl));
            }
        }

        // ---- x-transpose of next chunk (layer-0 blocks only, b = jb) ----
        if (layer == 0 && (s & 63) == 0 && s <= 384) {
            const int c = (s >> 6) + 1;            // chunks 1..7
            const int slot = c & 1;
            const int b = jb;                       // own batch row
            float* tileF = PfF;                     // [64][65]
#pragma unroll 1
            for (int i = 0; i < 9; ++i) {
                const int f0 = i * 64;
#pragma unroll
                for (int rr = 0; rr < 16; ++rr) {
                    const int fl = (tid >> 6) + rr * 4;
                    const int tt2 = tid & 63;
                    const int f = f0 + fl;
                    tileF[fl * 65 + tt2] = (f < FF) ? x[((size_t)b * FF + f) * TT + c * 64 + tt2] : 0.f;
                }
                __syncthreads();
                {
                    const int q = tid & 3, tt2 = tid >> 2;
                    const int fq = f0 + q * 16;
                    if (fq < KX) {
                        s16x8 vh0, vl0, vh1, vl1;
#pragma unroll
                        for (int m = 0; m < 8; ++m) {
                            short hi, lo; bfsplit(tileF[(q * 16 + m) * 65 + tt2], hi, lo);
                            vh0[m] = hi; vl0[m] = lo;
                        }
#pragma unroll
                        for (int m = 0; m < 8; ++m) {
                            short hi, lo; bfsplit(tileF[(q * 16 + 8 + m) * 65 + tt2], hi, lo);
                            vh1[m] = hi; vl1[m] = lo;
                        }
                        size_t o = (size_t)slot * XCH2 + ((size_t)tt2 * 64 + b) * KX + fq;
                        astore8(Xh + o,      lo4(vh0));
                        astore8(Xh + o + 4,  hi4(vh0));
                        astore8(Xh + o + 8,  lo4(vh1));
                        astore8(Xh + o + 12, hi4(vh1));
                        astore8(Xl + o,      lo4(vl0));
                        astore8(Xl + o + 4,  hi4(vl0));
                        astore8(Xl + o + 8,  lo4(vl1));
                        astore8(Xl + o + 12, hi4(vl1));
                    }
                }
                __syncthreads();
            }
            asm volatile("s_waitcnt vmcnt(0)" ::: "memory");   // drain all waves' x stores
        }

        // ---- flag completion of super-step s ----
        __syncthreads();
        if (tid == 0) {
            asm volatile("s_waitcnt vmcnt(0)" ::: "memory");   // drain wave0's h stores
            __hip_atomic_store(&arrive[bid * 32], (unsigned)(s + 1),
                               __ATOMIC_RELAXED, __HIP_MEMORY_SCOPE_AGENT);
        }
    }
}

// ---------- final FCs ----------
__global__ __launch_bounds__(256) void fc1_k(
    const short* __restrict__ H3h, const short* __restrict__ H3l,
    const float* __restrict__ W, const float* __restrict__ bias,
    float* __restrict__ hid)
{
    const int lane = (int)threadIdx.x & 63;                  // = b
    const int wv = __builtin_amdgcn_readfirstlane((int)threadIdx.x >> 6);
    const int n = (int)blockIdx.x * 4 + wv;                  // 0..511
    float acc = 0.f;
    const float* wr = W + (size_t)n * HH;
    for (int k = 0; k < HH; k += 8) {
        s16x8 vh = *(const s16x8*)(H3h + (size_t)lane * HH + k);
        s16x8 vl = *(const s16x8*)(H3l + (size_t)lane * HH + k);
#pragma unroll
        for (int i = 0; i < 8; ++i)
            acc = fmaf(bf2f(vh[i]) + bf2f(vl[i]), wr[k + i], acc);
    }
    acc += bias[n];
    hid[(size_t)lane * HH + n] = fmaxf(acc, 0.f);
}

__global__ __launch_bounds__(256) void fc2_k(
    const float* __restrict__ hid, const float* __restrict__ W,
    const float* __restrict__ bias, float* __restrict__ out)
{
    const int lane = (int)threadIdx.x & 63;                  // = b
    const int wv = __builtin_amdgcn_readfirstlane((int)threadIdx.x >> 6);
    const int n = (int)blockIdx.x * 4 + wv;                  // 0..515
    if (n >= FF) return;
    float acc = 0.f;
    const float* wr = W + (size_t)n * HH;
    const float* hp = hid + (size_t)lane * HH;
    for (int k = 0; k < HH; k += 8) {
        float4 a = *(const float4*)(hp + k);
        float4 b = *(const float4*)(hp + k + 4);
        acc = fmaf(a.x, wr[k+0], acc); acc = fmaf(a.y, wr[k+1], acc);
        acc = fmaf(a.z, wr[k+2], acc); acc = fmaf(a.w, wr[k+3], acc);
        acc = fmaf(b.x, wr[k+4], acc); acc = fmaf(b.y, wr[k+5], acc);
        acc = fmaf(b.z, wr[k+6], acc); acc = fmaf(b.w, wr[k+7], acc);
    }
    out[(size_t)lane * FF + n] = acc + bias[n];
}

extern "C" void kernel_launch(void* const* d_in, const int* in_sizes, int n_in,
                              void* d_out, int out_size, void* d_ws, size_t ws_size,
                              hipStream_t stream)
{
    const float* x     = (const float*)d_in[0];
    const float* Wih1  = (const float*)d_in[1];
    const float* Whh1  = (const float*)d_in[2];
    const float* bih1  = (const float*)d_in[3];
    const float* bhh1  = (const float*)d_in[4];
    const float* Wih2  = (const float*)d_in[5];
    const float* Whh2  = (const float*)d_in[6];
    const float* bih2  = (const float*)d_in[7];
    const float* bhh2  = (const float*)d_in[8];
    const float* Wih3  = (const float*)d_in[9];
    const float* Whh3  = (const float*)d_in[10];
    const float* bih3  = (const float*)d_in[11];
    const float* bhh3  = (const float*)d_in[12];
    const float* fc1_w = (const float*)d_in[13];
    const float* fc1_b = (const float*)d_in[14];
    const float* fc2_w = (const float*)d_in[15];
    const float* fc2_b = (const float*)d_in[16];

    char* p = (char*)d_ws;
    unsigned* arrive = (unsigned*)p;    // GRID*32 u32 slots (128B-padded)
    p = (char*)d_ws + 32768;            // round barrier region
    float* cT   = (float*)p;            p += (size_t)3 * HH * BB * 4;
    float* hid  = (float*)p;            p += (size_t)HH * BB * 4;
    float* bsum = (float*)p;            p += 6144 * 4;
    short* Hh   = (short*)p;            p += (size_t)6 * SBH * 2;
    short* Hl   = (short*)p;            p += (size_t)6 * SBH * 2;
    short* Xh   = (short*)p;            p += (size_t)2 * XCH2 * 2;
    short* Xl   = (short*)p;            p += (size_t)2 * XCH2 * 2;
    short* Bh   = (short*)p;            p += (size_t)TOTB * 2;
    short* Bl   = (short*)p;            p += (size_t)TOTB * 2;
    if ((size_t)(p - (char*)d_ws) > ws_size) return;

    hipMemsetAsync(d_ws, 0, 32768, stream);
    prep_state_h<<<384, 256, 0, stream>>>(
        (const float*)d_in[17], (const float*)d_in[19], (const float*)d_in[21], Hh, Hl);
    prep_state_c<<<24, 256, 0, stream>>>(
        (const float*)d_in[18], (const float*)d_in[20], (const float*)d_in[22], cT);
    prep_bias<<<24, 256, 0, stream>>>(bih1, bhh1, bih2, bhh2, bih3, bhh3, bsum);
    prep_blob<<<TOTB / 256, 256, 0, stream>>>(Wih1, Whh1, Wih2, Whh2, Wih3, Whh3, Bh, Bl);
    prep_x<<<576, 256, 0, stream>>>(x, Xh, Xl, 0);

    lstm_persist<<<GRID, 256, 0, stream>>>(x, Bh, Bl, Xh, Xl, Hh, Hl, bsum, cT, arrive);

    // final h3 @ t=511 -> slot (511+1)&1 = 0 -> layer2 slot0 = +4*SBH
    fc1_k<<<128, 256, 0, stream>>>(Hh + (size_t)4 * SBH, Hl + (size_t)4 * SBH,
                                   fc1_w, fc1_b, hid);
    fc2_k<<<129, 256, 0, stream>>>(hid, fc2_w, fc2_b, (float*)d_out);
}

// Round 9
// 5891.532 us; speedup vs baseline: 2.9588x; 1.5938x over previous
//
#include <hip/hip_runtime.h>
#include <math.h>

// 3-layer LSTM (B=64,H=512,T=512,F=513) + FC(512)->ReLU->FC(513).
// R8: R7 (persistent, register-resident split-bf16 MFMA weights, MALL-coherent
//     fence-free exchange) + FRAGMENT-LINEAR h blobs:
//  h stored as [it(16)][bt(4)][half(2)][lane(64)][4 shorts] per layer-slot, so
//  consumer A-fragments load at lane*8B stride (contiguous 512B per wave-instr,
//  4x128B MALL transactions) instead of rl*1088B stride (16x32B). 4x fewer
//  transactions on the dominant h-path. x path unchanged (row-major).

#define BB 64
#define HH 512
#define TT 512
#define FF 513
#define KX 544                 // padded x-K (17 tiles of 32)
#define KT1 33                 // L1 k-tiles (17 x + 16 h)
#define KT23 32
#define SBH 32768              // shorts per h slot (64*512)
#define XCH2 (64 * 64 * KX)    // shorts per x ring slot: 2,228,224
#define OFF2 2162688
#define OFF3 4259840
#define TOTB 6356992
#define GRID 192

typedef __attribute__((ext_vector_type(8))) short s16x8;
typedef __attribute__((ext_vector_type(4))) short s16x4;
typedef __attribute__((ext_vector_type(4))) float f32x4;

#define MFB(a, b, c) __builtin_amdgcn_mfma_f32_16x16x32_bf16(a, b, c, 0, 0, 0)

__device__ __forceinline__ float sigf(float x) { return 1.0f / (1.0f + expf(-x)); }

__device__ __forceinline__ float bf2f(short s) {
    return __uint_as_float(((unsigned)(unsigned short)s) << 16);
}
__device__ __forceinline__ short f2bf(float w) {   // RNE
    unsigned u = __float_as_uint(w);
    return (short)((u + 0x7fff + ((u >> 16) & 1)) >> 16);
}
__device__ __forceinline__ void bfsplit(float w, short& hi, short& lo) {
    hi = f2bf(w);
    lo = f2bf(w - bf2f(hi));
}
__device__ __forceinline__ s16x8 cat44(s16x4 a, s16x4 b) {
    s16x8 r;
    r[0]=a[0]; r[1]=a[1]; r[2]=a[2]; r[3]=a[3];
    r[4]=b[0]; r[5]=b[1]; r[6]=b[2]; r[7]=b[3];
    return r;
}

// ---- MALL-coherent 8B payload ops (agent-scope relaxed atomics) ----
__device__ __forceinline__ s16x4 aload8(const short* p) {
    unsigned long long v = __hip_atomic_load((const unsigned long long*)p,
                            __ATOMIC_RELAXED, __HIP_MEMORY_SCOPE_AGENT);
    union { unsigned long long u; s16x4 s; } c; c.u = v; return c.s;
}
__device__ __forceinline__ void astore8(short* p, s16x4 v) {
    union { unsigned long long u; s16x4 s; } c; c.s = v;
    __hip_atomic_store((unsigned long long*)p, c.u,
                       __ATOMIC_RELAXED, __HIP_MEMORY_SCOPE_AGENT);
}
__device__ __forceinline__ s16x4 lo4(s16x8 v) {
    s16x4 r; r[0]=v[0]; r[1]=v[1]; r[2]=v[2]; r[3]=v[3]; return r;
}
__device__ __forceinline__ s16x4 hi4(s16x8 v) {
    s16x4 r; r[0]=v[4]; r[1]=v[5]; r[2]=v[6]; r[3]=v[7]; return r;
}

// Fragment-blob address for h element (b, k) within one layer-slot blob:
//  it=k>>5, o32=k&31, half=o32>>4, w=o32&15, g=w>>2, i=w&3, bt=b>>4, rl=b&15
//  addr = ((it*4+bt)*2 + half)*256 + (g*16+rl)*4 + i      [shorts]
__device__ __forceinline__ int hfrag_addr(int b, int k) {
    int it = k >> 5, o32 = k & 31;
    int half = o32 >> 4, w = o32 & 15;
    int g = w >> 2, i = w & 3;
    int bt = b >> 4, rl = b & 15;
    return (((it * 4 + bt) * 2 + half) * 256) + (g * 16 + rl) * 4 + i;
}

// ---------- prep: initial h -> FRAGMENT-LINEAR bf16 hi/lo, slot 0 ----------
__global__ __launch_bounds__(256) void prep_state_h(
    const float* __restrict__ h1, const float* __restrict__ h2,
    const float* __restrict__ h3, short* __restrict__ Hh, short* __restrict__ Hl)
{
    int idx = blockIdx.x * 256 + threadIdx.x;          // 3*32768
    int l = idx >> 15, e = idx & 32767;
    int b = e >> 9, u = e & 511;
    const float* s = l == 0 ? h1 : l == 1 ? h2 : h3;
    short hi, lo; bfsplit(s[e], hi, lo);
    int fa = hfrag_addr(b, u);
    Hh[(size_t)(l * 2) * SBH + fa] = hi;
    Hl[(size_t)(l * 2) * SBH + fa] = lo;
}

// ---------- prep: initial c transpose [b][u] -> cT[l][u][b] ----------
__global__ __launch_bounds__(256) void prep_state_c(
    const float* __restrict__ c1, const float* __restrict__ c2,
    const float* __restrict__ c3, float* __restrict__ cT)
{
    __shared__ float tile[64][65];
    int l = blockIdx.x >> 3, ut = blockIdx.x & 7;
    const float* s = l == 0 ? c1 : l == 1 ? c2 : c3;
    int u0 = ut * 64, tid = threadIdx.x;
#pragma unroll
    for (int p = 0; p < 16; ++p) {
        int b = p * 4 + (tid >> 6), u = tid & 63;
        tile[u][b] = s[(size_t)b * HH + u0 + u];
    }
    __syncthreads();
#pragma unroll
    for (int p = 0; p < 16; ++p) {
        int ul = p * 4 + (tid >> 6), b = tid & 63;
        cT[(size_t)l * (HH * BB) + (size_t)(u0 + ul) * BB + b] = tile[ul][b];
    }
}

// ---------- prep: bias sums, gate-interleaved j' = 4u+g ----------
__global__ __launch_bounds__(256) void prep_bias(
    const float* __restrict__ bi1, const float* __restrict__ bh1,
    const float* __restrict__ bi2, const float* __restrict__ bh2,
    const float* __restrict__ bi3, const float* __restrict__ bh3,
    float* __restrict__ bsum)
{
    int idx = blockIdx.x * 256 + threadIdx.x;          // 3*2048
    if (idx >= 6144) return;
    int l = idx >> 11, jq = idx & 2047;
    int u = jq >> 2, g = jq & 3;
    const float* bi = l == 0 ? bi1 : l == 1 ? bi2 : bi3;
    const float* bh = l == 0 ? bh1 : l == 1 ? bh2 : bh3;
    bsum[idx] = bi[g * HH + u] + bh[g * HH + u];
}

// ---------- prep: weight blobs (fragment-linear, split hi/lo) ----------
__global__ __launch_bounds__(256) void prep_blob(
    const float* __restrict__ Wih1, const float* __restrict__ Whh1,
    const float* __restrict__ Wih2, const float* __restrict__ Whh2,
    const float* __restrict__ Wih3, const float* __restrict__ Whh3,
    short* __restrict__ Bh, short* __restrict__ Bl)
{
    int idx = blockIdx.x * 256 + threadIdx.x;          // TOTB exact
    int l, e, KTl;
    if (idx < OFF2)      { l = 0; e = idx;        KTl = KT1;  }
    else if (idx < OFF3) { l = 1; e = idx - OFF2; KTl = KT23; }
    else                 { l = 2; e = idx - OFF3; KTl = KT23; }
    int jtkt = e >> 9, r = e & 511;
    int lane = r >> 3, i = r & 7;
    int jt = jtkt / KTl, kt = jtkt - jt * KTl;
    int n = lane & 15, g = (lane >> 4) & 3;
    int jq = jt * 16 + n;
    int u = jq >> 2, gate = jq & 3;
    int row = gate * HH + u;
    int kk = kt * 32 + ((i < 4) ? (g * 4 + i) : (16 + g * 4 + (i - 4)));
    float w;
    if (l == 0) {
        if (kk < KX) w = (kk < FF) ? Wih1[(size_t)row * FF + kk] : 0.f;
        else         w = Whh1[(size_t)row * HH + (kk - KX)];
    } else if (l == 1) {
        w = (kk < HH) ? Wih2[(size_t)row * HH + kk] : Whh2[(size_t)row * HH + kk - HH];
    } else {
        w = (kk < HH) ? Wih3[(size_t)row * HH + kk] : Whh3[(size_t)row * HH + kk - HH];
    }
    short hi, lo; bfsplit(w, hi, lo);
    Bh[idx] = hi; Bl[idx] = lo;
}

// ---------- prep: x chunk 0 -> slot 0: [tt][b][544] hi/lo (row-major) ----------
__global__ __launch_bounds__(256) void prep_x(
    const float* __restrict__ x, short* __restrict__ Xh, short* __restrict__ Xl, int c)
{
    __shared__ float tile[64][65];
    int b = blockIdx.x / 9, fg = blockIdx.x - b * 9;
    int t0 = c * 64, tid = threadIdx.x;
#pragma unroll
    for (int p = 0; p < 16; ++p) {
        int idx = p * 256 + tid;
        int fl = idx >> 6, tt = idx & 63;
        int f = fg * 64 + fl;
        tile[fl][tt] = (f < FF) ? x[((size_t)b * FF + f) * TT + t0 + tt] : 0.f;
    }
    __syncthreads();
#pragma unroll
    for (int p = 0; p < 2; ++p) {
        int idx = p * 256 + tid;
        int fg8 = idx & 7, tt = idx >> 3;
        int k0 = fg * 64 + fg8 * 8;
        if (k0 < KX) {
            s16x8 vh, vl;
#pragma unroll
            for (int q = 0; q < 8; ++q) {
                short hi, lo; bfsplit(tile[fg8 * 8 + q][tt], hi, lo);
                vh[q] = hi; vl[q] = lo;
            }
            size_t off = ((size_t)tt * BB + b) * KX + k0;
            *(s16x8*)(Xh + off) = vh;
            *(s16x8*)(Xl + off) = vl;
        }
    }
}

// ---------- THE persistent kernel ----------
__global__ __launch_bounds__(256, 1) void lstm_persist(
    const float* __restrict__ x,
    const short* __restrict__ Bh, const short* __restrict__ Bl,
    short* __restrict__ Xh, short* __restrict__ Xl,
    short* __restrict__ Hh, short* __restrict__ Hl,
    const float* __restrict__ bsum, const float* __restrict__ cTin,
    unsigned* __restrict__ arrive)   // [GRID * 32] (128B-padded slots)
{
    __shared__ float PfF[4 * 32 * 65];     // 33280 B; also aliased as x-tile [64][65]
    __shared__ float cLDS[8 * 64];
    __shared__ float biasLDS[32];
    __shared__ short hstH[64 * 8];
    __shared__ short hstL[64 * 8];

    const int bid = (int)blockIdx.x;
    const int layer = bid >> 6;            // 0..2
    const int jb = bid & 63;               // 0..63 -> j' cols [jb*32, jb*32+32)
    const int tid = (int)threadIdx.x;
    const int lane = tid & 63;
    const int wv = __builtin_amdgcn_readfirstlane(tid >> 6);
    const int rl = lane & 15, g = lane >> 4;
    const int u0 = jb * 8;

    // per-wave K split
    int kt0, ktn;
    if (layer == 0) { if (wv == 0) { kt0 = 0; ktn = 9; } else { kt0 = 9 + 8 * (wv - 1); ktn = 8; } }
    else            { kt0 = wv * 8; ktn = 8; }
    const int KTl = (layer == 0) ? KT1 : KT23;
    const size_t blobOff = (layer == 0) ? 0 : ((layer == 1) ? (size_t)OFF2 : (size_t)OFF3);

    // ---- weights -> registers (once) ----
    s16x8 WHr[2][9], WLr[2][9];
#pragma unroll
    for (int jj = 0; jj < 2; ++jj) {
        const int jtG = jb * 2 + jj;
#pragma unroll
        for (int it = 0; it < 9; ++it) {
            if (it < ktn) {
                size_t o = blobOff + ((size_t)(jtG * KTl + kt0 + it)) * 512 + lane * 8;
                WHr[jj][it] = *(const s16x8*)(Bh + o);
                WLr[jj][it] = *(const s16x8*)(Bl + o);
            }
        }
    }

    // ---- c slice + bias -> LDS (once) ----
    for (int e = tid; e < 512; e += 256)
        cLDS[e] = cTin[(size_t)layer * (HH * BB) + (size_t)u0 * 64 + e];
    if (tid < 32) biasLDS[tid] = bsum[layer * 2048 + jb * 32 + tid];
    __syncthreads();

    const bool need0 = (layer <= 1);   // group 0 flags
    const bool need2 = (layer >= 1);   // group 2 flags

    // producer-side fragment store geometry (block owns u0..u0+7)
    const int p_it = jb >> 2;                  // k-tile index of our u-cols
    const int p_o  = (jb & 3) * 8;             // offset within the 32-wide tile
    const int p_hf = (p_o >= 16) ? 1 : 0;
    const int p_gA = (p_o & 8) ? 2 : 0;        // lanes gA and gA+1

    for (int s = 0; s < TT + 2; ++s) {
        // ---- selective wait: dependency groups must have flagged >= s ----
        if (s > 0) {
            if (tid < 64) {
                const unsigned want = (unsigned)s;
                for (;;) {
                    bool ok = true;
                    if (need0)
                        ok &= __hip_atomic_load(&arrive[(0 * 64 + tid) * 32],
                              __ATOMIC_RELAXED, __HIP_MEMORY_SCOPE_AGENT) >= want;
                    ok &= __hip_atomic_load(&arrive[(1 * 64 + tid) * 32],
                          __ATOMIC_RELAXED, __HIP_MEMORY_SCOPE_AGENT) >= want;
                    if (need2)
                        ok &= __hip_atomic_load(&arrive[(2 * 64 + tid) * 32],
                              __ATOMIC_RELAXED, __HIP_MEMORY_SCOPE_AGENT) >= want;
                    if (__all(ok)) break;
                    __builtin_amdgcn_s_sleep(1);
                }
            }
            __syncthreads();
        }

        const int t = s - layer;
        if (t >= 0 && t < TT) {
            // ---- A sources ----
            const bool isX = (layer == 0 && wv < 2);
            const short* pAH = nullptr; const short* pAL = nullptr;   // x path
            const short* frH = nullptr; const short* frL = nullptr;   // h frag path
            int itg0 = 0;
            if (layer == 0) {
                if (wv < 2) {
                    size_t xb = (size_t)((t >> 6) & 1) * XCH2 + (size_t)(t & 63) * (64 * KX);
                    pAH = Xh + xb + (size_t)rl * KX + kt0 * 32 + g * 4;
                    pAL = Xl + xb + (size_t)rl * KX + kt0 * 32 + g * 4;
                } else {
                    size_t hb = (size_t)(0 * 2 + (t & 1)) * SBH;
                    frH = Hh + hb; frL = Hl + hb; itg0 = kt0 - 17;
                }
            } else if (layer == 1) {
                size_t hb;
                if (wv < 2) { hb = (size_t)(0 * 2 + ((t + 1) & 1)) * SBH; itg0 = kt0; }
                else        { hb = (size_t)(1 * 2 + (t & 1)) * SBH; itg0 = kt0 - 16; }
                frH = Hh + hb; frL = Hl + hb;
            } else {
                size_t hb;
                if (wv < 2) { hb = (size_t)(1 * 2 + ((t + 1) & 1)) * SBH; itg0 = kt0; }
                else        { hb = (size_t)(2 * 2 + (t & 1)) * SBH; itg0 = kt0 - 16; }
                frH = Hh + hb; frL = Hl + hb;
            }

            f32x4 acc[2][4];
#pragma unroll
            for (int jj = 0; jj < 2; ++jj)
#pragma unroll
                for (int bt = 0; bt < 4; ++bt) acc[jj][bt] = (f32x4){0.f, 0.f, 0.f, 0.f};

#pragma unroll
            for (int it = 0; it < 9; ++it) {
                if (it < ktn) {
                    s16x8 aH[4], aL[4];
                    if (isX) {
                        const int ko = it * 32;
#pragma unroll
                        for (int bt = 0; bt < 4; ++bt) {
                            const short* ph = pAH + ko + (size_t)(bt * 16) * KX;
                            const short* pl = pAL + ko + (size_t)(bt * 16) * KX;
                            aH[bt] = cat44(aload8(ph), aload8(ph + 16));
                            aL[bt] = cat44(aload8(pl), aload8(pl + 16));
                        }
                    } else {
                        const int fb = (itg0 + it) * 4;
#pragma unroll
                        for (int bt = 0; bt < 4; ++bt) {
                            const int fo = (fb + bt) * 512 + lane * 4;
                            aH[bt] = cat44(aload8(frH + fo), aload8(frH + fo + 256));
                            aL[bt] = cat44(aload8(frL + fo), aload8(frL + fo + 256));
                        }
                    }
#pragma unroll
                    for (int jj = 0; jj < 2; ++jj) {
#pragma unroll
                        for (int bt = 0; bt < 4; ++bt) {
                            acc[jj][bt] = MFB(aH[bt], WHr[jj][it], acc[jj][bt]);
                            acc[jj][bt] = MFB(aL[bt], WHr[jj][it], acc[jj][bt]);
                            acc[jj][bt] = MFB(aH[bt], WLr[jj][it], acc[jj][bt]);
                        }
                    }
                }
            }

            // ---- partial reduce across 4 waves ----
#pragma unroll
            for (int jj = 0; jj < 2; ++jj)
#pragma unroll
                for (int bt = 0; bt < 4; ++bt)
#pragma unroll
                    for (int r = 0; r < 4; ++r)
                        PfF[(wv * 32 + jj * 16 + rl) * 65 + bt * 16 + g * 4 + r] = acc[jj][bt][r];
            __syncthreads();

            {   // gates + pointwise: thread = (ul = tid>>5, bl = tid&31), 2 b-halves
                const int ul = tid >> 5, bl = tid & 31;
#pragma unroll
                for (int half = 0; half < 2; ++half) {
                    const int b = bl + half * 32;
                    float G[4];
#pragma unroll
                    for (int gi = 0; gi < 4; ++gi) {
                        const int jl = ul * 4 + gi;
                        float v = PfF[(0 * 32 + jl) * 65 + b] + PfF[(1 * 32 + jl) * 65 + b]
                                + PfF[(2 * 32 + jl) * 65 + b] + PfF[(3 * 32 + jl) * 65 + b];
                        G[gi] = v + biasLDS[jl];
                    }
                    float cold = cLDS[ul * 64 + b];
                    float cn = sigf(G[1]) * cold + sigf(G[0]) * tanhf(G[2]);
                    float hn = sigf(G[3]) * tanhf(cn);
                    cLDS[ul * 64 + b] = cn;
                    short hi, lo; bfsplit(hn, hi, lo);
                    hstH[b * 8 + ul] = hi;
                    hstL[b * 8 + ul] = lo;
                }
            }
            __syncthreads();
            if (tid < 64) {   // write h slice -> FRAGMENT-LINEAR blob (MALL-coherent)
                const int b = tid, bt = b >> 4, prl = b & 15;
                const size_t base = (size_t)(layer * 2 + ((t + 1) & 1)) * SBH
                                  + (size_t)((p_it * 4 + bt) * 2 + p_hf) * 256;
                const size_t aA = base + (size_t)(p_gA * 16 + prl) * 4;
                const size_t aB = base + (size_t)((p_gA + 1) * 16 + prl) * 4;
                s16x8 vh = *(const s16x8*)(hstH + b * 8);
                s16x8 vl = *(const s16x8*)(hstL + b * 8);
                astore8(Hh + aA, lo4(vh));
                astore8(Hh + aB, hi4(vh));
                astore8(Hl + aA, lo4(vl));
                astore8(Hl + aB, hi4(vl));
            }
        }

        // ---- x-transpose of next chunk (layer-0 blocks only, b = jb) ----
        if (layer == 0 && (s & 63) == 0 && s <= 384) {
            const int c = (s >> 6) + 1;            // chunks 1..7
            const int slot = c & 1;
            const int b = jb;                       // own batch row
            float* tileF = PfF;                     // [64][65]
#pragma unroll 1
            for (int i = 0; i < 9; ++i) {
                const int f0 = i * 64;
#pragma unroll
                for (int rr = 0; rr < 16; ++rr) {
                    const int fl = (tid >> 6) + rr * 4;
                    const int tt2 = tid & 63;
                    const int f = f0 + fl;
                    tileF[fl * 65 + tt2] = (f < FF) ? x[((size_t)b * FF + f) * TT + c * 64 + tt2] : 0.f;
                }
                __syncthreads();
                {
                    const int q = tid & 3, tt2 = tid >> 2;
                    const int fq = f0 + q * 16;
                    if (fq < KX) {
                        s16x8 vh0, vl0, vh1, vl1;
#pragma unroll
                        for (int m = 0; m < 8; ++m) {
                            short hi, lo; bfsplit(tileF[(q * 16 + m) * 65 + tt2], hi, lo);
                            vh0[m] = hi; vl0[m] = lo;
                        }
#pragma unroll
                        for (int m = 0; m < 8; ++m) {
                            short hi, lo; bfsplit(tileF[(q * 16 + 8 + m) * 65 + tt2], hi, lo);
                            vh1[m] = hi; vl1[m] = lo;
                        }
                        size_t o = (size_t)slot * XCH2 + ((size_t)tt2 * 64 + b) * KX + fq;
                        astore8(Xh + o,      lo4(vh0));
                        astore8(Xh + o + 4,  hi4(vh0));
                        astore8(Xh + o + 8,  lo4(vh1));
                        astore8(Xh + o + 12, hi4(vh1));
                        astore8(Xl + o,      lo4(vl0));
                        astore8(Xl + o + 4,  hi4(vl0));
                        astore8(Xl + o + 8,  lo4(vl1));
                        astore8(Xl + o + 12, hi4(vl1));
                    }
                }
                __syncthreads();
            }
            asm volatile("s_waitcnt vmcnt(0)" ::: "memory");   // drain all waves' x stores
        }

        // ---- flag completion of super-step s ----
        __syncthreads();
        if (tid == 0) {
            asm volatile("s_waitcnt vmcnt(0)" ::: "memory");   // drain wave0's h stores
            __hip_atomic_store(&arrive[bid * 32], (unsigned)(s + 1),
                               __ATOMIC_RELAXED, __HIP_MEMORY_SCOPE_AGENT);
        }
    }
}

// ---------- final FCs (fc1 reads fragment-layout h3) ----------
__global__ __launch_bounds__(256) void fc1_k(
    const short* __restrict__ H3h, const short* __restrict__ H3l,
    const float* __restrict__ W, const float* __restrict__ bias,
    float* __restrict__ hid)
{
    const int lane = (int)threadIdx.x & 63;                  // = b
    const int wv = __builtin_amdgcn_readfirstlane((int)threadIdx.x >> 6);
    const int n = (int)blockIdx.x * 4 + wv;                  // 0..511
    const int bt = lane >> 4, rl = lane & 15;
    float acc = 0.f;
    const float* wr = W + (size_t)n * HH;
    for (int it = 0; it < 16; ++it) {
#pragma unroll
        for (int hf = 0; hf < 2; ++hf) {
#pragma unroll
            for (int g4 = 0; g4 < 4; ++g4) {
                const int k = it * 32 + hf * 16 + g4 * 4;
                const int fa = ((it * 4 + bt) * 2 + hf) * 256 + (g4 * 16 + rl) * 4;
                s16x4 vh = *(const s16x4*)(H3h + fa);
                s16x4 vl = *(const s16x4*)(H3l + fa);
#pragma unroll
                for (int i = 0; i < 4; ++i)
                    acc = fmaf(bf2f(vh[i]) + bf2f(vl[i]), wr[k + i], acc);
            }
        }
    }
    acc += bias[n];
    hid[(size_t)lane * HH + n] = fmaxf(acc, 0.f);
}

__global__ __launch_bounds__(256) void fc2_k(
    const float* __restrict__ hid, const float* __restrict__ W,
    const float* __restrict__ bias, float* __restrict__ out)
{
    const int lane = (int)threadIdx.x & 63;                  // = b
    const int wv = __builtin_amdgcn_readfirstlane((int)threadIdx.x >> 6);
    const int n = (int)blockIdx.x * 4 + wv;                  // 0..515
    if (n >= FF) return;
    float acc = 0.f;
    const float* wr = W + (size_t)n * HH;
    const float* hp = hid + (size_t)lane * HH;
    for (int k = 0; k < HH; k += 8) {
        float4 a = *(const float4*)(hp + k);
        float4 b = *(const float4*)(hp + k + 4);
        acc = fmaf(a.x, wr[k+0], acc); acc = fmaf(a.y, wr[k+1], acc);
        acc = fmaf(a.z, wr[k+2], acc); acc = fmaf(a.w, wr[k+3], acc);
        acc = fmaf(b.x, wr[k+4], acc); acc = fmaf(b.y, wr[k+5], acc);
        acc = fmaf(b.z, wr[k+6], acc); acc = fmaf(b.w, wr[k+7], acc);
    }
    out[(size_t)lane * FF + n] = acc + bias[n];
}

extern "C" void kernel_launch(void* const* d_in, const int* in_sizes, int n_in,
                              void* d_out, int out_size, void* d_ws, size_t ws_size,
                              hipStream_t stream)
{
    const float* x     = (const float*)d_in[0];
    const float* Wih1  = (const float*)d_in[1];
    const float* Whh1  = (const float*)d_in[2];
    const float* bih1  = (const float*)d_in[3];
    const float* bhh1  = (const float*)d_in[4];
    const float* Wih2  = (const float*)d_in[5];
    const float* Whh2  = (const float*)d_in[6];
    const float* bih2  = (const float*)d_in[7];
    const float* bhh2  = (const float*)d_in[8];
    const float* Wih3  = (const float*)d_in[9];
    const float* Whh3  = (const float*)d_in[10];
    const float* bih3  = (const float*)d_in[11];
    const float* bhh3  = (const float*)d_in[12];
    const float* fc1_w = (const float*)d_in[13];
    const float* fc1_b = (const float*)d_in[14];
    const float* fc2_w = (const float*)d_in[15];
    const float* fc2_b = (const float*)d_in[16];

    char* p = (char*)d_ws;
    unsigned* arrive = (unsigned*)p;    // GRID*32 u32 slots (128B-padded)
    p = (char*)d_ws + 32768;            // round barrier region
    float* cT   = (float*)p;            p += (size_t)3 * HH * BB * 4;
    float* hid  = (float*)p;            p += (size_t)HH * BB * 4;
    float* bsum = (float*)p;            p += 6144 * 4;
    short* Hh   = (short*)p;            p += (size_t)6 * SBH * 2;
    short* Hl   = (short*)p;            p += (size_t)6 * SBH * 2;
    short* Xh   = (short*)p;            p += (size_t)2 * XCH2 * 2;
    short* Xl   = (short*)p;            p += (size_t)2 * XCH2 * 2;
    short* Bh   = (short*)p;            p += (size_t)TOTB * 2;
    short* Bl   = (short*)p;            p += (size_t)TOTB * 2;
    if ((size_t)(p - (char*)d_ws) > ws_size) return;

    hipMemsetAsync(d_ws, 0, 32768, stream);
    prep_state_h<<<384, 256, 0, stream>>>(
        (const float*)d_in[17], (const float*)d_in[19], (const float*)d_in[21], Hh, Hl);
    prep_state_c<<<24, 256, 0, stream>>>(
        (const float*)d_in[18], (const float*)d_in[20], (const float*)d_in[22], cT);
    prep_bias<<<24, 256, 0, stream>>>(bih1, bhh1, bih2, bhh2, bih3, bhh3, bsum);
    prep_blob<<<TOTB / 256, 256, 0, stream>>>(Wih1, Whh1, Wih2, Whh2, Wih3, Whh3, Bh, Bl);
    prep_x<<<576, 256, 0, stream>>>(x, Xh, Xl, 0);

    lstm_persist<<<GRID, 256, 0, stream>>>(x, Bh, Bl, Xh, Xl, Hh, Hl, bsum, cT, arrive);

    // final h3 @ t=511 -> slot (511+1)&1 = 0 -> layer2 slot0 = +4*SBH
    fc1_k<<<128, 256, 0, stream>>>(Hh + (size_t)4 * SBH, Hl + (size_t)4 * SBH,
                                   fc1_w, fc1_b, hid);
    fc2_k<<<129, 256, 0, stream>>>(hid, fc2_w, fc2_b, (float*)d_out);
}

// Round 10
// 5871.257 us; speedup vs baseline: 2.9690x; 1.0035x over previous
//
#include <hip/hip_runtime.h>
#include <math.h>

// 3-layer LSTM (B=64,H=512,T=512,F=513) + FC(512)->ReLU->FC(513).
// R9: R8 (persistent, register-resident split-bf16 MFMA weights, MALL-coherent
//     fence-free exchange, fragment-linear h blobs) + AGGREGATED sync:
//  - per-layer aggregator block (jb==63) gathers its group's 64 arrive slots
//    (64 lanes, 1 line each) and publishes ONE monotone go3[layer] word;
//  - consumers poll <=3 go-words with a single lane.
//  R8's 64-lane x 192-line poll per block per iteration (~185 MB/epoch of MALL
//  traffic) was saturating the Infinity Cache; this cuts poll traffic ~60x.

#define BB 64
#define HH 512
#define TT 512
#define FF 513
#define KX 544                 // padded x-K (17 tiles of 32)
#define KT1 33                 // L1 k-tiles (17 x + 16 h)
#define KT23 32
#define SBH 32768              // shorts per h slot (64*512)
#define XCH2 (64 * 64 * KX)    // shorts per x ring slot: 2,228,224
#define OFF2 2162688
#define OFF3 4259840
#define TOTB 6356992
#define GRID 192

typedef __attribute__((ext_vector_type(8))) short s16x8;
typedef __attribute__((ext_vector_type(4))) short s16x4;
typedef __attribute__((ext_vector_type(4))) float f32x4;

#define MFB(a, b, c) __builtin_amdgcn_mfma_f32_16x16x32_bf16(a, b, c, 0, 0, 0)

__device__ __forceinline__ float sigf(float x) { return 1.0f / (1.0f + expf(-x)); }

__device__ __forceinline__ float bf2f(short s) {
    return __uint_as_float(((unsigned)(unsigned short)s) << 16);
}
__device__ __forceinline__ short f2bf(float w) {   // RNE
    unsigned u = __float_as_uint(w);
    return (short)((u + 0x7fff + ((u >> 16) & 1)) >> 16);
}
__device__ __forceinline__ void bfsplit(float w, short& hi, short& lo) {
    hi = f2bf(w);
    lo = f2bf(w - bf2f(hi));
}
__device__ __forceinline__ s16x8 cat44(s16x4 a, s16x4 b) {
    s16x8 r;
    r[0]=a[0]; r[1]=a[1]; r[2]=a[2]; r[3]=a[3];
    r[4]=b[0]; r[5]=b[1]; r[6]=b[2]; r[7]=b[3];
    return r;
}

// ---- MALL-coherent 8B payload ops (agent-scope relaxed atomics) ----
__device__ __forceinline__ s16x4 aload8(const short* p) {
    unsigned long long v = __hip_atomic_load((const unsigned long long*)p,
                            __ATOMIC_RELAXED, __HIP_MEMORY_SCOPE_AGENT);
    union { unsigned long long u; s16x4 s; } c; c.u = v; return c.s;
}
__device__ __forceinline__ void astore8(short* p, s16x4 v) {
    union { unsigned long long u; s16x4 s; } c; c.s = v;
    __hip_atomic_store((unsigned long long*)p, c.u,
                       __ATOMIC_RELAXED, __HIP_MEMORY_SCOPE_AGENT);
}
__device__ __forceinline__ s16x4 lo4(s16x8 v) {
    s16x4 r; r[0]=v[0]; r[1]=v[1]; r[2]=v[2]; r[3]=v[3]; return r;
}
__device__ __forceinline__ s16x4 hi4(s16x8 v) {
    s16x4 r; r[0]=v[4]; r[1]=v[5]; r[2]=v[6]; r[3]=v[7]; return r;
}

// Fragment-blob address for h element (b, k) within one layer-slot blob:
//  it=k>>5, o32=k&31, half=o32>>4, w=o32&15, g=w>>2, i=w&3, bt=b>>4, rl=b&15
//  addr = ((it*4+bt)*2 + half)*256 + (g*16+rl)*4 + i      [shorts]
__device__ __forceinline__ int hfrag_addr(int b, int k) {
    int it = k >> 5, o32 = k & 31;
    int half = o32 >> 4, w = o32 & 15;
    int g = w >> 2, i = w & 3;
    int bt = b >> 4, rl = b & 15;
    return (((it * 4 + bt) * 2 + half) * 256) + (g * 16 + rl) * 4 + i;
}

// ---------- prep: initial h -> FRAGMENT-LINEAR bf16 hi/lo, slot 0 ----------
__global__ __launch_bounds__(256) void prep_state_h(
    const float* __restrict__ h1, const float* __restrict__ h2,
    const float* __restrict__ h3, short* __restrict__ Hh, short* __restrict__ Hl)
{
    int idx = blockIdx.x * 256 + threadIdx.x;          // 3*32768
    int l = idx >> 15, e = idx & 32767;
    int b = e >> 9, u = e & 511;
    const float* s = l == 0 ? h1 : l == 1 ? h2 : h3;
    short hi, lo; bfsplit(s[e], hi, lo);
    int fa = hfrag_addr(b, u);
    Hh[(size_t)(l * 2) * SBH + fa] = hi;
    Hl[(size_t)(l * 2) * SBH + fa] = lo;
}

// ---------- prep: initial c transpose [b][u] -> cT[l][u][b] ----------
__global__ __launch_bounds__(256) void prep_state_c(
    const float* __restrict__ c1, const float* __restrict__ c2,
    const float* __restrict__ c3, float* __restrict__ cT)
{
    __shared__ float tile[64][65];
    int l = blockIdx.x >> 3, ut = blockIdx.x & 7;
    const float* s = l == 0 ? c1 : l == 1 ? c2 : c3;
    int u0 = ut * 64, tid = threadIdx.x;
#pragma unroll
    for (int p = 0; p < 16; ++p) {
        int b = p * 4 + (tid >> 6), u = tid & 63;
        tile[u][b] = s[(size_t)b * HH + u0 + u];
    }
    __syncthreads();
#pragma unroll
    for (int p = 0; p < 16; ++p) {
        int ul = p * 4 + (tid >> 6), b = tid & 63;
        cT[(size_t)l * (HH * BB) + (size_t)(u0 + ul) * BB + b] = tile[ul][b];
    }
}

// ---------- prep: bias sums, gate-interleaved j' = 4u+g ----------
__global__ __launch_bounds__(256) void prep_bias(
    const float* __restrict__ bi1, const float* __restrict__ bh1,
    const float* __restrict__ bi2, const float* __restrict__ bh2,
    const float* __restrict__ bi3, const float* __restrict__ bh3,
    float* __restrict__ bsum)
{
    int idx = blockIdx.x * 256 + threadIdx.x;          // 3*2048
    if (idx >= 6144) return;
    int l = idx >> 11, jq = idx & 2047;
    int u = jq >> 2, g = jq & 3;
    const float* bi = l == 0 ? bi1 : l == 1 ? bi2 : bi3;
    const float* bh = l == 0 ? bh1 : l == 1 ? bh2 : bh3;
    bsum[idx] = bi[g * HH + u] + bh[g * HH + u];
}

// ---------- prep: weight blobs (fragment-linear, split hi/lo) ----------
__global__ __launch_bounds__(256) void prep_blob(
    const float* __restrict__ Wih1, const float* __restrict__ Whh1,
    const float* __restrict__ Wih2, const float* __restrict__ Whh2,
    const float* __restrict__ Wih3, const float* __restrict__ Whh3,
    short* __restrict__ Bh, short* __restrict__ Bl)
{
    int idx = blockIdx.x * 256 + threadIdx.x;          // TOTB exact
    int l, e, KTl;
    if (idx < OFF2)      { l = 0; e = idx;        KTl = KT1;  }
    else if (idx < OFF3) { l = 1; e = idx - OFF2; KTl = KT23; }
    else                 { l = 2; e = idx - OFF3; KTl = KT23; }
    int jtkt = e >> 9, r = e & 511;
    int lane = r >> 3, i = r & 7;
    int jt = jtkt / KTl, kt = jtkt - jt * KTl;
    int n = lane & 15, g = (lane >> 4) & 3;
    int jq = jt * 16 + n;
    int u = jq >> 2, gate = jq & 3;
    int row = gate * HH + u;
    int kk = kt * 32 + ((i < 4) ? (g * 4 + i) : (16 + g * 4 + (i - 4)));
    float w;
    if (l == 0) {
        if (kk < KX) w = (kk < FF) ? Wih1[(size_t)row * FF + kk] : 0.f;
        else         w = Whh1[(size_t)row * HH + (kk - KX)];
    } else if (l == 1) {
        w = (kk < HH) ? Wih2[(size_t)row * HH + kk] : Whh2[(size_t)row * HH + kk - HH];
    } else {
        w = (kk < HH) ? Wih3[(size_t)row * HH + kk] : Whh3[(size_t)row * HH + kk - HH];
    }
    short hi, lo; bfsplit(w, hi, lo);
    Bh[idx] = hi; Bl[idx] = lo;
}

// ---------- prep: x chunk 0 -> slot 0: [tt][b][544] hi/lo (row-major) ----------
__global__ __launch_bounds__(256) void prep_x(
    const float* __restrict__ x, short* __restrict__ Xh, short* __restrict__ Xl, int c)
{
    __shared__ float tile[64][65];
    int b = blockIdx.x / 9, fg = blockIdx.x - b * 9;
    int t0 = c * 64, tid = threadIdx.x;
#pragma unroll
    for (int p = 0; p < 16; ++p) {
        int idx = p * 256 + tid;
        int fl = idx >> 6, tt = idx & 63;
        int f = fg * 64 + fl;
        tile[fl][tt] = (f < FF) ? x[((size_t)b * FF + f) * TT + t0 + tt] : 0.f;
    }
    __syncthreads();
#pragma unroll
    for (int p = 0; p < 2; ++p) {
        int idx = p * 256 + tid;
        int fg8 = idx & 7, tt = idx >> 3;
        int k0 = fg * 64 + fg8 * 8;
        if (k0 < KX) {
            s16x8 vh, vl;
#pragma unroll
            for (int q = 0; q < 8; ++q) {
                short hi, lo; bfsplit(tile[fg8 * 8 + q][tt], hi, lo);
                vh[q] = hi; vl[q] = lo;
            }
            size_t off = ((size_t)tt * BB + b) * KX + k0;
            *(s16x8*)(Xh + off) = vh;
            *(s16x8*)(Xl + off) = vl;
        }
    }
}

// ---------- THE persistent kernel ----------
__global__ __launch_bounds__(256, 1) void lstm_persist(
    const float* __restrict__ x,
    const short* __restrict__ Bh, const short* __restrict__ Bl,
    short* __restrict__ Xh, short* __restrict__ Xl,
    short* __restrict__ Hh, short* __restrict__ Hl,
    const float* __restrict__ bsum, const float* __restrict__ cTin,
    unsigned* __restrict__ arrive,   // [GRID * 32] (128B-padded slots)
    unsigned* __restrict__ go3)      // [3 * 32]  (128B-padded go-words)
{
    __shared__ float PfF[4 * 32 * 65];     // 33280 B; also aliased as x-tile [64][65]
    __shared__ float cLDS[8 * 64];
    __shared__ float biasLDS[32];
    __shared__ short hstH[64 * 8];
    __shared__ short hstL[64 * 8];

    const int bid = (int)blockIdx.x;
    const int layer = bid >> 6;            // 0..2
    const int jb = bid & 63;               // 0..63 -> j' cols [jb*32, jb*32+32)
    const int tid = (int)threadIdx.x;
    const int lane = tid & 63;
    const int wv = __builtin_amdgcn_readfirstlane(tid >> 6);
    const int rl = lane & 15, g = lane >> 4;
    const int u0 = jb * 8;

    // per-wave K split
    int kt0, ktn;
    if (layer == 0) { if (wv == 0) { kt0 = 0; ktn = 9; } else { kt0 = 9 + 8 * (wv - 1); ktn = 8; } }
    else            { kt0 = wv * 8; ktn = 8; }
    const int KTl = (layer == 0) ? KT1 : KT23;
    const size_t blobOff = (layer == 0) ? 0 : ((layer == 1) ? (size_t)OFF2 : (size_t)OFF3);

    // ---- weights -> registers (once) ----
    s16x8 WHr[2][9], WLr[2][9];
#pragma unroll
    for (int jj = 0; jj < 2; ++jj) {
        const int jtG = jb * 2 + jj;
#pragma unroll
        for (int it = 0; it < 9; ++it) {
            if (it < ktn) {
                size_t o = blobOff + ((size_t)(jtG * KTl + kt0 + it)) * 512 + lane * 8;
                WHr[jj][it] = *(const s16x8*)(Bh + o);
                WLr[jj][it] = *(const s16x8*)(Bl + o);
            }
        }
    }

    // ---- c slice + bias -> LDS (once) ----
    for (int e = tid; e < 512; e += 256)
        cLDS[e] = cTin[(size_t)layer * (HH * BB) + (size_t)u0 * 64 + e];
    if (tid < 32) biasLDS[tid] = bsum[layer * 2048 + jb * 32 + tid];
    __syncthreads();

    const bool need0 = (layer <= 1);   // group 0 go-word
    const bool need2 = (layer >= 1);   // group 2 go-word

    // producer-side fragment store geometry (block owns u0..u0+7)
    const int p_it = jb >> 2;                  // k-tile index of our u-cols
    const int p_o  = (jb & 3) * 8;             // offset within the 32-wide tile
    const int p_hf = (p_o >= 16) ? 1 : 0;
    const int p_gA = (p_o & 8) ? 2 : 0;        // lanes gA and gA+1

    for (int s = 0; s < TT + 2; ++s) {
        // ---- wait: needed groups' go-words >= s (single-lane poll) ----
        if (s > 0) {
            if (tid == 0) {
                const unsigned want = (unsigned)s;
                for (;;) {
                    bool ok = true;
                    if (need0)
                        ok &= __hip_atomic_load(&go3[0],
                              __ATOMIC_RELAXED, __HIP_MEMORY_SCOPE_AGENT) >= want;
                    ok &= __hip_atomic_load(&go3[32],
                          __ATOMIC_RELAXED, __HIP_MEMORY_SCOPE_AGENT) >= want;
                    if (need2)
                        ok &= __hip_atomic_load(&go3[64],
                              __ATOMIC_RELAXED, __HIP_MEMORY_SCOPE_AGENT) >= want;
                    if (ok) break;
                    __builtin_amdgcn_s_sleep(1);
                }
            }
            __syncthreads();
        }

        const int t = s - layer;
        if (t >= 0 && t < TT) {
            // ---- A sources ----
            const bool isX = (layer == 0 && wv < 2);
            const short* pAH = nullptr; const short* pAL = nullptr;   // x path
            const short* frH = nullptr; const short* frL = nullptr;   // h frag path
            int itg0 = 0;
            if (layer == 0) {
                if (wv < 2) {
                    size_t xb = (size_t)((t >> 6) & 1) * XCH2 + (size_t)(t & 63) * (64 * KX);
                    pAH = Xh + xb + (size_t)rl * KX + kt0 * 32 + g * 4;
                    pAL = Xl + xb + (size_t)rl * KX + kt0 * 32 + g * 4;
                } else {
                    size_t hb = (size_t)(0 * 2 + (t & 1)) * SBH;
                    frH = Hh + hb; frL = Hl + hb; itg0 = kt0 - 17;
                }
            } else if (layer == 1) {
                size_t hb;
                if (wv < 2) { hb = (size_t)(0 * 2 + ((t + 1) & 1)) * SBH; itg0 = kt0; }
                else        { hb = (size_t)(1 * 2 + (t & 1)) * SBH; itg0 = kt0 - 16; }
                frH = Hh + hb; frL = Hl + hb;
            } else {
                size_t hb;
                if (wv < 2) { hb = (size_t)(1 * 2 + ((t + 1) & 1)) * SBH; itg0 = kt0; }
                else        { hb = (size_t)(2 * 2 + (t & 1)) * SBH; itg0 = kt0 - 16; }
                frH = Hh + hb; frL = Hl + hb;
            }

            f32x4 acc[2][4];
#pragma unroll
            for (int jj = 0; jj < 2; ++jj)
#pragma unroll
                for (int bt = 0; bt < 4; ++bt) acc[jj][bt] = (f32x4){0.f, 0.f, 0.f, 0.f};

#pragma unroll
            for (int it = 0; it < 9; ++it) {
                if (it < ktn) {
                    s16x8 aH[4], aL[4];
                    if (isX) {
                        const int ko = it * 32;
#pragma unroll
                        for (int bt = 0; bt < 4; ++bt) {
                            const short* ph = pAH + ko + (size_t)(bt * 16) * KX;
                            const short* pl = pAL + ko + (size_t)(bt * 16) * KX;
                            aH[bt] = cat44(aload8(ph), aload8(ph + 16));
                            aL[bt] = cat44(aload8(pl), aload8(pl + 16));
                        }
                    } else {
                        const int fb = (itg0 + it) * 4;
#pragma unroll
                        for (int bt = 0; bt < 4; ++bt) {
                            const int fo = (fb + bt) * 512 + lane * 4;
                            aH[bt] = cat44(aload8(frH + fo), aload8(frH + fo + 256));
                            aL[bt] = cat44(aload8(frL + fo), aload8(frL + fo + 256));
                        }
                    }
#pragma unroll
                    for (int jj = 0; jj < 2; ++jj) {
#pragma unroll
                        for (int bt = 0; bt < 4; ++bt) {
                            acc[jj][bt] = MFB(aH[bt], WHr[jj][it], acc[jj][bt]);
                            acc[jj][bt] = MFB(aL[bt], WHr[jj][it], acc[jj][bt]);
                            acc[jj][bt] = MFB(aH[bt], WLr[jj][it], acc[jj][bt]);
                        }
                    }
                }
            }

            // ---- partial reduce across 4 waves ----
#pragma unroll
            for (int jj = 0; jj < 2; ++jj)
#pragma unroll
                for (int bt = 0; bt < 4; ++bt)
#pragma unroll
                    for (int r = 0; r < 4; ++r)
                        PfF[(wv * 32 + jj * 16 + rl) * 65 + bt * 16 + g * 4 + r] = acc[jj][bt][r];
            __syncthreads();

            {   // gates + pointwise: thread = (ul = tid>>5, bl = tid&31), 2 b-halves
                const int ul = tid >> 5, bl = tid & 31;
#pragma unroll
                for (int half = 0; half < 2; ++half) {
                    const int b = bl + half * 32;
                    float G[4];
#pragma unroll
                    for (int gi = 0; gi < 4; ++gi) {
                        const int jl = ul * 4 + gi;
                        float v = PfF[(0 * 32 + jl) * 65 + b] + PfF[(1 * 32 + jl) * 65 + b]
                                + PfF[(2 * 32 + jl) * 65 + b] + PfF[(3 * 32 + jl) * 65 + b];
                        G[gi] = v + biasLDS[jl];
                    }
                    float cold = cLDS[ul * 64 + b];
                    float cn = sigf(G[1]) * cold + sigf(G[0]) * tanhf(G[2]);
                    float hn = sigf(G[3]) * tanhf(cn);
                    cLDS[ul * 64 + b] = cn;
                    short hi, lo; bfsplit(hn, hi, lo);
                    hstH[b * 8 + ul] = hi;
                    hstL[b * 8 + ul] = lo;
                }
            }
            __syncthreads();
            if (tid < 64) {   // write h slice -> FRAGMENT-LINEAR blob (MALL-coherent)
                const int b = tid, bt = b >> 4, prl = b & 15;
                const size_t base = (size_t)(layer * 2 + ((t + 1) & 1)) * SBH
                                  + (size_t)((p_it * 4 + bt) * 2 + p_hf) * 256;
                const size_t aA = base + (size_t)(p_gA * 16 + prl) * 4;
                const size_t aB = base + (size_t)((p_gA + 1) * 16 + prl) * 4;
                s16x8 vh = *(const s16x8*)(hstH + b * 8);
                s16x8 vl = *(const s16x8*)(hstL + b * 8);
                astore8(Hh + aA, lo4(vh));
                astore8(Hh + aB, hi4(vh));
                astore8(Hl + aA, lo4(vl));
                astore8(Hl + aB, hi4(vl));
            }
        }

        // ---- x-transpose of next chunk (layer-0 blocks only, b = jb) ----
        if (layer == 0 && (s & 63) == 0 && s <= 384) {
            const int c = (s >> 6) + 1;            // chunks 1..7
            const int slot = c & 1;
            const int b = jb;                       // own batch row
            float* tileF = PfF;                     // [64][65]
#pragma unroll 1
            for (int i = 0; i < 9; ++i) {
                const int f0 = i * 64;
#pragma unroll
                for (int rr = 0; rr < 16; ++rr) {
                    const int fl = (tid >> 6) + rr * 4;
                    const int tt2 = tid & 63;
                    const int f = f0 + fl;
                    tileF[fl * 65 + tt2] = (f < FF) ? x[((size_t)b * FF + f) * TT + c * 64 + tt2] : 0.f;
                }
                __syncthreads();
                {
                    const int q = tid & 3, tt2 = tid >> 2;
                    const int fq = f0 + q * 16;
                    if (fq < KX) {
                        s16x8 vh0, vl0, vh1, vl1;
#pragma unroll
                        for (int m = 0; m < 8; ++m) {
                            short hi, lo; bfsplit(tileF[(q * 16 + m) * 65 + tt2], hi, lo);
                            vh0[m] = hi; vl0[m] = lo;
                        }
#pragma unroll
                        for (int m = 0; m < 8; ++m) {
                            short hi, lo; bfsplit(tileF[(q * 16 + 8 + m) * 65 + tt2], hi, lo);
                            vh1[m] = hi; vl1[m] = lo;
                        }
                        size_t o = (size_t)slot * XCH2 + ((size_t)tt2 * 64 + b) * KX + fq;
                        astore8(Xh + o,      lo4(vh0));
                        astore8(Xh + o + 4,  hi4(vh0));
                        astore8(Xh + o + 8,  lo4(vh1));
                        astore8(Xh + o + 12, hi4(vh1));
                        astore8(Xl + o,      lo4(vl0));
                        astore8(Xl + o + 4,  hi4(vl0));
                        astore8(Xl + o + 8,  lo4(vl1));
                        astore8(Xl + o + 12, hi4(vl1));
                    }
                }
                __syncthreads();
            }
            asm volatile("s_waitcnt vmcnt(0)" ::: "memory");   // drain all waves' x stores
        }

        // ---- flag completion of super-step s; aggregator publishes go3 ----
        __syncthreads();
        if (tid == 0) {
            asm volatile("s_waitcnt vmcnt(0)" ::: "memory");   // drain wave0's h stores
            __hip_atomic_store(&arrive[bid * 32], (unsigned)(s + 1),
                               __ATOMIC_RELAXED, __HIP_MEMORY_SCOPE_AGENT);
        }
        if (jb == 63 && tid < 64) {   // aggregator: gather own group's 64 slots
            const unsigned want = (unsigned)(s + 1);
            for (;;) {
                unsigned v = __hip_atomic_load(&arrive[(layer * 64 + tid) * 32],
                              __ATOMIC_RELAXED, __HIP_MEMORY_SCOPE_AGENT);
                if (__all(v >= want)) break;
                __builtin_amdgcn_s_sleep(1);
            }
            if (tid == 0)
                __hip_atomic_store(&go3[layer * 32], want,
                                   __ATOMIC_RELAXED, __HIP_MEMORY_SCOPE_AGENT);
        }
    }
}

// ---------- final FCs (fc1 reads fragment-layout h3) ----------
__global__ __launch_bounds__(256) void fc1_k(
    const short* __restrict__ H3h, const short* __restrict__ H3l,
    const float* __restrict__ W, const float* __restrict__ bias,
    float* __restrict__ hid)
{
    const int lane = (int)threadIdx.x & 63;                  // = b
    const int wv = __builtin_amdgcn_readfirstlane((int)threadIdx.x >> 6);
    const int n = (int)blockIdx.x * 4 + wv;                  // 0..511
    const int bt = lane >> 4, rl = lane & 15;
    float acc = 0.f;
    const float* wr = W + (size_t)n * HH;
    for (int it = 0; it < 16; ++it) {
#pragma unroll
        for (int hf = 0; hf < 2; ++hf) {
#pragma unroll
            for (int g4 = 0; g4 < 4; ++g4) {
                const int k = it * 32 + hf * 16 + g4 * 4;
                const int fa = ((it * 4 + bt) * 2 + hf) * 256 + (g4 * 16 + rl) * 4;
                s16x4 vh = *(const s16x4*)(H3h + fa);
                s16x4 vl = *(const s16x4*)(H3l + fa);
#pragma unroll
                for (int i = 0; i < 4; ++i)
                    acc = fmaf(bf2f(vh[i]) + bf2f(vl[i]), wr[k + i], acc);
            }
        }
    }
    acc += bias[n];
    hid[(size_t)lane * HH + n] = fmaxf(acc, 0.f);
}

__global__ __launch_bounds__(256) void fc2_k(
    const float* __restrict__ hid, const float* __restrict__ W,
    const float* __restrict__ bias, float* __restrict__ out)
{
    const int lane = (int)threadIdx.x & 63;                  // = b
    const int wv = __builtin_amdgcn_readfirstlane((int)threadIdx.x >> 6);
    const int n = (int)blockIdx.x * 4 + wv;                  // 0..515
    if (n >= FF) return;
    float acc = 0.f;
    const float* wr = W + (size_t)n * HH;
    const float* hp = hid + (size_t)lane * HH;
    for (int k = 0; k < HH; k += 8) {
        float4 a = *(const float4*)(hp + k);
        float4 b = *(const float4*)(hp + k + 4);
        acc = fmaf(a.x, wr[k+0], acc); acc = fmaf(a.y, wr[k+1], acc);
        acc = fmaf(a.z, wr[k+2], acc); acc = fmaf(a.w, wr[k+3], acc);
        acc = fmaf(b.x, wr[k+4], acc); acc = fmaf(b.y, wr[k+5], acc);
        acc = fmaf(b.z, wr[k+6], acc); acc = fmaf(b.w, wr[k+7], acc);
    }
    out[(size_t)lane * FF + n] = acc + bias[n];
}

extern "C" void kernel_launch(void* const* d_in, const int* in_sizes, int n_in,
                              void* d_out, int out_size, void* d_ws, size_t ws_size,
                              hipStream_t stream)
{
    const float* x     = (const float*)d_in[0];
    const float* Wih1  = (const float*)d_in[1];
    const float* Whh1  = (const float*)d_in[2];
    const float* bih1  = (const float*)d_in[3];
    const float* bhh1  = (const float*)d_in[4];
    const float* Wih2  = (const float*)d_in[5];
    const float* Whh2  = (const float*)d_in[6];
    const float* bih2  = (const float*)d_in[7];
    const float* bhh2  = (const float*)d_in[8];
    const float* Wih3  = (const float*)d_in[9];
    const float* Whh3  = (const float*)d_in[10];
    const float* bih3  = (const float*)d_in[11];
    const float* bhh3  = (const float*)d_in[12];
    const float* fc1_w = (const float*)d_in[13];
    const float* fc1_b = (const float*)d_in[14];
    const float* fc2_w = (const float*)d_in[15];
    const float* fc2_b = (const float*)d_in[16];

    char* p = (char*)d_ws;
    unsigned* arrive = (unsigned*)p;                       // GRID*32 u32 slots
    unsigned* go3    = (unsigned*)(p + (size_t)GRID * 32 * 4);  // 3*32 u32 slots
    p = (char*)d_ws + 32768;            // round barrier region
    float* cT   = (float*)p;            p += (size_t)3 * HH * BB * 4;
    float* hid  = (float*)p;            p += (size_t)HH * BB * 4;
    float* bsum = (float*)p;            p += 6144 * 4;
    short* Hh   = (short*)p;            p += (size_t)6 * SBH * 2;
    short* Hl   = (short*)p;            p += (size_t)6 * SBH * 2;
    short* Xh   = (short*)p;            p += (size_t)2 * XCH2 * 2;
    short* Xl   = (short*)p;            p += (size_t)2 * XCH2 * 2;
    short* Bh   = (short*)p;            p += (size_t)TOTB * 2;
    short* Bl   = (short*)p;            p += (size_t)TOTB * 2;
    if ((size_t)(p - (char*)d_ws) > ws_size) return;

    hipMemsetAsync(d_ws, 0, 32768, stream);
    prep_state_h<<<384, 256, 0, stream>>>(
        (const float*)d_in[17], (const float*)d_in[19], (const float*)d_in[21], Hh, Hl);
    prep_state_c<<<24, 256, 0, stream>>>(
        (const float*)d_in[18], (const float*)d_in[20], (const float*)d_in[22], cT);
    prep_bias<<<24, 256, 0, stream>>>(bih1, bhh1, bih2, bhh2, bih3, bhh3, bsum);
    prep_blob<<<TOTB / 256, 256, 0, stream>>>(Wih1, Whh1, Wih2, Whh2, Wih3, Whh3, Bh, Bl);
    prep_x<<<576, 256, 0, stream>>>(x, Xh, Xl, 0);

    lstm_persist<<<GRID, 256, 0, stream>>>(x, Bh, Bl, Xh, Xl, Hh, Hl, bsum, cT,
                                           arrive, go3);

    // final h3 @ t=511 -> slot (511+1)&1 = 0 -> layer2 slot0 = +4*SBH
    fc1_k<<<128, 256, 0, stream>>>(Hh + (size_t)4 * SBH, Hl + (size_t)4 * SBH,
                                   fc1_w, fc1_b, hid);
    fc2_k<<<129, 256, 0, stream>>>(hid, fc2_w, fc2_b, (float*)d_out);
}